// Round 14
// baseline (2721.564 us; speedup 1.0000x reference)
//
#include <hip/hip_runtime.h>
#include <hip/hip_bf16.h>
#include <math.h>

#define B_  256
#define S_  200
#define F_  10
#define T_  100
#define E_  128
#define H_  256
#define G4  1024   // 4*H
#define P1_ 512
#define P2_ 128

typedef __attribute__((ext_vector_type(8))) short short8;
typedef __attribute__((ext_vector_type(4))) float f32x4;
typedef _Float16 half2f __attribute__((ext_vector_type(2)));

#if __has_builtin(__builtin_amdgcn_fdot2)
#define FDOT2(w2, h2, acc) __builtin_amdgcn_fdot2((w2), (h2), (acc), false)
#else
#define FDOT2(w2, h2, acc) ((acc) + (float)((w2)[0]) * (float)((h2)[0]) + (float)((w2)[1]) * (float)((h2)[1]))
#endif
#define BCH2(u) __builtin_bit_cast(half2f, (u))

// scan W placement: 32 kpair rows in LDS (stride 36), 96 rows x 4 cols in regs
#define NL3_ 32
#define NV3_ 96
#define LDW3 36

__device__ __forceinline__ float sigf(float x) { return 1.0f / (1.0f + expf(-x)); }
__device__ __forceinline__ float bf2f(ushort u) { return __uint_as_float(((uint)u) << 16); }
__device__ __forceinline__ ushort f2bf(float f) {
    __hip_bfloat16 v = __float2bfloat16(f);
    return *(ushort*)&v;
}
__device__ __forceinline__ ushort f2h(float f) {
    _Float16 h = (_Float16)f;
    return __builtin_bit_cast(ushort, h);
}
__device__ __forceinline__ float h2f(ushort u) {
    return (float)__builtin_bit_cast(_Float16, u);
}

__global__ __launch_bounds__(256) void k_bsum(const float* __restrict__ bi,
                                              const float* __restrict__ bh,
                                              float* __restrict__ bs) {
    int i = blockIdx.x * 256 + threadIdx.x;
    if (i < G4) bs[i] = bi[i] + bh[i];
}

// W (R x C) f32 -> WT (C x R) bf16. grid (C/32, R/32), 256 thr.
__global__ __launch_bounds__(256) void k_tr_bf16(const float* __restrict__ W,
                                                 ushort* __restrict__ WT,
                                                 int R, int C) {
    __shared__ float t[32][33];
    int c0 = blockIdx.x * 32, r0 = blockIdx.y * 32;
    int lc = threadIdx.x & 31, lr = threadIdx.x >> 5;
    #pragma unroll
    for (int i = 0; i < 4; ++i)
        t[lr + 8 * i][lc] = W[(long)(r0 + lr + 8 * i) * C + c0 + lc];
    __syncthreads();
    #pragma unroll
    for (int i = 0; i < 4; ++i)
        WT[(long)(c0 + lr + 8 * i) * R + r0 + lc] = f2bf(t[lc][lr + 8 * i]);
}

// W_hh (1024 x 256) f32 -> WPu: k-pair-interleaved fp16.
// WPu[kp*1024 + c] = pack(f16(W[c][2kp]), f16(W[c][2kp+1])), kp=0..127.
__global__ __launch_bounds__(256) void k_prep_wp(const float* __restrict__ W,
                                                 uint* __restrict__ WPu) {
    __shared__ float t[32][33];
    int k0 = blockIdx.x * 32, c0 = blockIdx.y * 32;
    int lk = threadIdx.x & 31, lc8 = threadIdx.x >> 5;
    #pragma unroll
    for (int i = 0; i < 4; ++i)
        t[lc8 + 8 * i][lk] = W[(long)(c0 + lc8 + 8 * i) * 256 + k0 + lk];
    __syncthreads();
    int kpl = threadIdx.x >> 4;   // 0..15
    int ccl = threadIdx.x & 15;   // 0..15
    #pragma unroll
    for (int hf = 0; hf < 2; ++hf) {
        int c = ccl + 16 * hf;
        uint lo = f2h(t[c][2 * kpl]);
        uint hi = f2h(t[c][2 * kpl + 1]);
        WPu[(long)(k0 / 2 + kpl) * G4 + c0 + c] = lo | (hi << 16);
    }
}

__global__ __launch_bounds__(256) void k_cvt_bf16(const float* __restrict__ W,
                                                  ushort* __restrict__ O, int n) {
    int i = blockIdx.x * 256 + threadIdx.x;
    if (i < n) O[i] = f2bf(W[i]);
}

// two (b,s) rows per block; 256 threads; bf16 out
__global__ __launch_bounds__(256) void k_gather(const int* __restrict__ x,
                                                const float* __restrict__ emb,
                                                ushort* __restrict__ e) {
    int bs = blockIdx.x * 2 + (threadIdx.x >> 7);
    int t  = threadIdx.x & 127;
    const int* xr = x + (long)bs * F_;
    float acc = 0.f;
    #pragma unroll
    for (int f = 0; f < F_; ++f) acc += emb[(long)xr[f] * E_ + t];
    e[(long)bs * E_ + t] = f2bf(acc * (1.0f / F_));
}

// ---------------- bf16 MFMA GEMM. OUTM: 0=f32, 1=bf16, 2=f16 ----------------
template<int ACT, int OUTM>
__global__ __launch_bounds__(256) void k_gemm_mfma(
    const ushort* __restrict__ A, int rowDiv, long sOuter, long sInner,
    const ushort* __restrict__ Bm,
    const float* __restrict__ bias,
    const float* __restrict__ rowAdd, int rowAddDiv,
    void* __restrict__ Cout, int N, int K)
{
    constexpr int LDT = 40;
    __shared__ ushort Al[128 * LDT];
    __shared__ ushort Bl[128 * LDT];
    int tid = threadIdx.x;
    int n0 = blockIdx.x * 128;
    int m0 = blockIdx.y * 128;

    int rA = tid >> 2, qA = tid & 3;
    int m_lo = m0 + rA, m_hi = m_lo + 64;
    long a0 = (long)(m_lo / rowDiv) * sOuter + (long)(m_lo % rowDiv) * sInner + qA * 8;
    long a1 = (long)(m_hi / rowDiv) * sOuter + (long)(m_hi % rowDiv) * sInner + qA * 8;
    const ushort* b0p = Bm + (long)(n0 + rA) * K + qA * 8;
    const ushort* b1p = Bm + (long)(n0 + rA + 64) * K + qA * 8;

    int lane = tid & 63, wave = tid >> 6;
    int wr = wave >> 1, wc = wave & 1;
    int lrow = lane & 15, lkh = lane >> 4;

    const f32x4 fz = {0.f, 0.f, 0.f, 0.f};
    f32x4 acc[4][4];
    #pragma unroll
    for (int i = 0; i < 4; ++i)
        #pragma unroll
        for (int j = 0; j < 4; ++j) acc[i][j] = fz;

    int nk = K >> 5;
    for (int kc = 0; kc < nk; ++kc) {
        uint4 va0 = *(const uint4*)(A + a0 + kc * 32);
        uint4 va1 = *(const uint4*)(A + a1 + kc * 32);
        uint4 vb0 = *(const uint4*)(b0p + kc * 32);
        uint4 vb1 = *(const uint4*)(b1p + kc * 32);
        *(uint4*)&Al[rA * LDT + qA * 8]        = va0;
        *(uint4*)&Al[(rA + 64) * LDT + qA * 8] = va1;
        *(uint4*)&Bl[rA * LDT + qA * 8]        = vb0;
        *(uint4*)&Bl[(rA + 64) * LDT + qA * 8] = vb1;
        __syncthreads();
        short8 af[4], bfr[4];
        #pragma unroll
        for (int mi = 0; mi < 4; ++mi)
            af[mi] = *(const short8*)&Al[(wr * 64 + mi * 16 + lrow) * LDT + lkh * 8];
        #pragma unroll
        for (int ni = 0; ni < 4; ++ni)
            bfr[ni] = *(const short8*)&Bl[(wc * 64 + ni * 16 + lrow) * LDT + lkh * 8];
        #pragma unroll
        for (int mi = 0; mi < 4; ++mi)
            #pragma unroll
            for (int ni = 0; ni < 4; ++ni)
                acc[mi][ni] = __builtin_amdgcn_mfma_f32_16x16x32_bf16(
                    af[mi], bfr[ni], acc[mi][ni], 0, 0, 0);
        __syncthreads();
    }
    #pragma unroll
    for (int mi = 0; mi < 4; ++mi) {
        #pragma unroll
        for (int r = 0; r < 4; ++r) {
            int m = m0 + wr * 64 + mi * 16 + lkh * 4 + r;
            long rowoff = rowAdd ? (long)(m / rowAddDiv) * N : 0;
            #pragma unroll
            for (int ni = 0; ni < 4; ++ni) {
                int n = n0 + wc * 64 + ni * 16 + lrow;
                float v = acc[mi][ni][r];
                if (bias)   v += bias[n];
                if (rowAdd) v += rowAdd[rowoff + n];
                if (ACT)    v = fmaxf(v, 0.f);
                if (OUTM == 1)      ((ushort*)Cout)[(long)m * N + n] = f2bf(v);
                else if (OUTM == 2) ((ushort*)Cout)[(long)m * N + n] = f2h(v);
                else                ((float*)Cout)[(long)m * N + n] = v;
            }
        }
    }
}

// ---------------- z2 GEMM with fused mlp3 epilogue ----------------
__global__ __launch_bounds__(256) void k_z2_fused(
    const ushort* __restrict__ A, const ushort* __restrict__ Bm,
    const float* __restrict__ b2, const float* __restrict__ W3,
    const float* __restrict__ b3, float* __restrict__ out)
{
    constexpr int LDT = 40;
    __shared__ ushort Al[128 * LDT];
    __shared__ ushort Bl[128 * LDT];
    __shared__ float Zl[128 * 132];
    int tid = threadIdx.x;
    int m0 = blockIdx.x * 128;
    const int K = P1_;

    int rA = tid >> 2, qA = tid & 3;
    const ushort* a0p = A + (long)(m0 + rA) * K + qA * 8;
    const ushort* a1p = A + (long)(m0 + rA + 64) * K + qA * 8;
    const ushort* b0p = Bm + (long)rA * K + qA * 8;
    const ushort* b1p = Bm + (long)(rA + 64) * K + qA * 8;

    int lane = tid & 63, wave = tid >> 6;
    int wr = wave >> 1, wc = wave & 1;
    int lrow = lane & 15, lkh = lane >> 4;

    const f32x4 fz = {0.f, 0.f, 0.f, 0.f};
    f32x4 acc[4][4];
    #pragma unroll
    for (int i = 0; i < 4; ++i)
        #pragma unroll
        for (int j = 0; j < 4; ++j) acc[i][j] = fz;

    for (int kc = 0; kc < K / 32; ++kc) {
        uint4 va0 = *(const uint4*)(a0p + kc * 32);
        uint4 va1 = *(const uint4*)(a1p + kc * 32);
        uint4 vb0 = *(const uint4*)(b0p + kc * 32);
        uint4 vb1 = *(const uint4*)(b1p + kc * 32);
        *(uint4*)&Al[rA * LDT + qA * 8]        = va0;
        *(uint4*)&Al[(rA + 64) * LDT + qA * 8] = va1;
        *(uint4*)&Bl[rA * LDT + qA * 8]        = vb0;
        *(uint4*)&Bl[(rA + 64) * LDT + qA * 8] = vb1;
        __syncthreads();
        short8 af[4], bfr[4];
        #pragma unroll
        for (int mi = 0; mi < 4; ++mi)
            af[mi] = *(const short8*)&Al[(wr * 64 + mi * 16 + lrow) * LDT + lkh * 8];
        #pragma unroll
        for (int ni = 0; ni < 4; ++ni)
            bfr[ni] = *(const short8*)&Bl[(wc * 64 + ni * 16 + lrow) * LDT + lkh * 8];
        #pragma unroll
        for (int mi = 0; mi < 4; ++mi)
            #pragma unroll
            for (int ni = 0; ni < 4; ++ni)
                acc[mi][ni] = __builtin_amdgcn_mfma_f32_16x16x32_bf16(
                    af[mi], bfr[ni], acc[mi][ni], 0, 0, 0);
        __syncthreads();
    }
    #pragma unroll
    for (int mi = 0; mi < 4; ++mi) {
        #pragma unroll
        for (int r = 0; r < 4; ++r) {
            int row = wr * 64 + mi * 16 + lkh * 4 + r;
            #pragma unroll
            for (int ni = 0; ni < 4; ++ni) {
                int col = wc * 64 + ni * 16 + lrow;
                Zl[row * 132 + col] = fmaxf(acc[mi][ni][r] + b2[col], 0.f);
            }
        }
    }
    __syncthreads();
    float w3a = W3[lane], w3b = W3[64 + lane], b3v = b3[0];
    for (int r = 0; r < 32; ++r) {
        int row = wave * 32 + r;
        float s = Zl[row * 132 + lane] * w3a + Zl[row * 132 + 64 + lane] * w3b;
        #pragma unroll
        for (int off = 32; off > 0; off >>= 1) s += __shfl_down(s, off);
        if (lane == 0) out[m0 + row] = sigf(s + b3v);
    }
}

// Persistent LSTM scan, W fully CU-resident. 256 threads/block (1 wave/SIMD
// -> ~512-reg cap), one block per batch row. Thread tid owns cols
// {tid, tid+256, tid+512, tid+768} = ALL FOUR GATES of cell tid -> cell
// update is thread-local (no act_s exchange). W kpair rows (packed fp16):
// rows 0..NL3_-1 in LDS [col][row] stride LDW3=36 (conflict-optimal, r12);
// rows NL3_..127 in VGPRs (4 arrays, static indexing). Nothing streamed.
__global__ __launch_bounds__(256, 1) void k_lstm_scan(
    const ushort* __restrict__ Xgh, const uint* __restrict__ WPu,
    float* __restrict__ hN, float* __restrict__ cN, ushort* __restrict__ hNb)
{
    extern __shared__ __align__(16) char smem[];
    uint*   Wl   = (uint*)smem;                     // [1024 cols][LDW3] uints
    uint*   h16u = (uint*)(smem + 1024 * LDW3 * 4); // 128 uints (packed f16 h)
    ushort* h16  = (ushort*)h16u;
    int tid = threadIdx.x;          // 0..255
    int b   = blockIdx.x;

    // one-time LDS W fill, transposed
    for (int i = tid; i < NL3_ * 1024; i += 256) {
        int row = i >> 10, col = i & 1023;
        Wl[col * LDW3 + row] = WPu[(long)row * G4 + col];
    }
    // one-time VGPR W fill: 96 rows x 4 cols
    uint w0r[NV3_], w1r[NV3_], w2r[NV3_], w3r[NV3_];
    #pragma unroll
    for (int i = 0; i < NV3_; ++i) {
        w0r[i] = WPu[(long)(NL3_ + i) * G4 + tid];
        w1r[i] = WPu[(long)(NL3_ + i) * G4 + tid + 256];
        w2r[i] = WPu[(long)(NL3_ + i) * G4 + tid + 512];
        w3r[i] = WPu[(long)(NL3_ + i) * G4 + tid + 768];
    }
    if (tid < 128) h16u[tid] = 0;
    float c_r = 0.f;
    __syncthreads();

    const ushort* xgp = Xgh + (long)b * T_ * G4;
    const uint* wc0 = Wl + (tid      ) * LDW3;
    const uint* wc1 = Wl + (tid + 256) * LDW3;
    const uint* wc2 = Wl + (tid + 512) * LDW3;
    const uint* wc3 = Wl + (tid + 768) * LDW3;

    for (int t = 0; t < T_; ++t) {
        float xv0 = h2f(xgp[(long)t * G4 + tid]);
        float xv1 = h2f(xgp[(long)t * G4 + tid + 256]);
        float xv2 = h2f(xgp[(long)t * G4 + tid + 512]);
        float xv3 = h2f(xgp[(long)t * G4 + tid + 768]);
        float s0a = 0.f, s0b = 0.f, s1a = 0.f, s1b = 0.f;
        float s2a = 0.f, s2b = 0.f, s3a = 0.f, s3b = 0.f;
        #pragma unroll
        for (int g = 0; g < NL3_ / 4; ++g) {            // LDS W rows (32)
            uint4 hh = *(const uint4*)(h16u + 4 * g);
            uint4 wa = *(const uint4*)(wc0 + 4 * g);
            uint4 wb = *(const uint4*)(wc1 + 4 * g);
            uint4 wc = *(const uint4*)(wc2 + 4 * g);
            uint4 wd = *(const uint4*)(wc3 + 4 * g);
            s0a = FDOT2(BCH2(wa.x), BCH2(hh.x), s0a); s0b = FDOT2(BCH2(wa.y), BCH2(hh.y), s0b);
            s0a = FDOT2(BCH2(wa.z), BCH2(hh.z), s0a); s0b = FDOT2(BCH2(wa.w), BCH2(hh.w), s0b);
            s1a = FDOT2(BCH2(wb.x), BCH2(hh.x), s1a); s1b = FDOT2(BCH2(wb.y), BCH2(hh.y), s1b);
            s1a = FDOT2(BCH2(wb.z), BCH2(hh.z), s1a); s1b = FDOT2(BCH2(wb.w), BCH2(hh.w), s1b);
            s2a = FDOT2(BCH2(wc.x), BCH2(hh.x), s2a); s2b = FDOT2(BCH2(wc.y), BCH2(hh.y), s2b);
            s2a = FDOT2(BCH2(wc.z), BCH2(hh.z), s2a); s2b = FDOT2(BCH2(wc.w), BCH2(hh.w), s2b);
            s3a = FDOT2(BCH2(wd.x), BCH2(hh.x), s3a); s3b = FDOT2(BCH2(wd.y), BCH2(hh.y), s3b);
            s3a = FDOT2(BCH2(wd.z), BCH2(hh.z), s3a); s3b = FDOT2(BCH2(wd.w), BCH2(hh.w), s3b);
        }
        #pragma unroll
        for (int g = 0; g < NV3_ / 4; ++g) {            // VGPR W rows (96)
            uint4 hh = *(const uint4*)(h16u + NL3_ + 4 * g);
            s0a = FDOT2(BCH2(w0r[4 * g + 0]), BCH2(hh.x), s0a);
            s0b = FDOT2(BCH2(w0r[4 * g + 1]), BCH2(hh.y), s0b);
            s0a = FDOT2(BCH2(w0r[4 * g + 2]), BCH2(hh.z), s0a);
            s0b = FDOT2(BCH2(w0r[4 * g + 3]), BCH2(hh.w), s0b);
            s1a = FDOT2(BCH2(w1r[4 * g + 0]), BCH2(hh.x), s1a);
            s1b = FDOT2(BCH2(w1r[4 * g + 1]), BCH2(hh.y), s1b);
            s1a = FDOT2(BCH2(w1r[4 * g + 2]), BCH2(hh.z), s1a);
            s1b = FDOT2(BCH2(w1r[4 * g + 3]), BCH2(hh.w), s1b);
            s2a = FDOT2(BCH2(w2r[4 * g + 0]), BCH2(hh.x), s2a);
            s2b = FDOT2(BCH2(w2r[4 * g + 1]), BCH2(hh.y), s2b);
            s2a = FDOT2(BCH2(w2r[4 * g + 2]), BCH2(hh.z), s2a);
            s2b = FDOT2(BCH2(w2r[4 * g + 3]), BCH2(hh.w), s2b);
            s3a = FDOT2(BCH2(w3r[4 * g + 0]), BCH2(hh.x), s3a);
            s3b = FDOT2(BCH2(w3r[4 * g + 1]), BCH2(hh.y), s3b);
            s3a = FDOT2(BCH2(w3r[4 * g + 2]), BCH2(hh.z), s3a);
            s3b = FDOT2(BCH2(w3r[4 * g + 3]), BCH2(hh.w), s3b);
        }
        float gi = sigf(s0a + s0b + xv0);
        float gf = sigf(s1a + s1b + xv1);
        float gg = tanhf(s2a + s2b + xv2);
        float go = sigf(s3a + s3b + xv3);
        float cn = gf * c_r + gi * gg;
        c_r = cn;
        float h = go * tanhf(cn);
        __syncthreads();            // all h reads of this step complete
        h16[tid] = f2h(h);
        if (t == T_ - 1) {
            hN[(long)b * H_ + tid] = h;
            cN[(long)b * H_ + tid] = c_r;
            hNb[(long)b * H_ + tid] = f2bf(h);
        }
        __syncthreads();            // h ready for next step
    }
}

// decode cell, bf16 gate input (Gdec written bf16 by MFMA GEMM)
__global__ __launch_bounds__(256) void k_dec_cell(const ushort* __restrict__ G,
                                                  const float* __restrict__ cNb,
                                                  ushort* __restrict__ hdec) {
    long idx = (long)blockIdx.x * 256 + threadIdx.x;
    int m = (int)(idx >> 8);
    int j = (int)(idx & 255);
    int b = m / T_;
    const ushort* g = G + (long)m * G4 + j;
    float gi = bf2f(g[0]), gf = bf2f(g[H_]);
    float gg = bf2f(g[2 * H_]), go = bf2f(g[3 * H_]);
    float cv = sigf(gf) * cNb[(long)b * H_ + j] + sigf(gi) * tanhf(gg);
    hdec[idx] = f2bf(sigf(go) * tanhf(cv));
}

extern "C" void kernel_launch(void* const* d_in, const int* in_sizes, int n_in,
                              void* d_out, int out_size, void* d_ws, size_t ws_size,
                              hipStream_t stream)
{
    const int*   x    = (const int*)d_in[0];
    const float* emb  = (const float*)d_in[1];
    const float* W_ih = (const float*)d_in[2];
    const float* W_hh = (const float*)d_in[3];
    const float* b_ih = (const float*)d_in[4];
    const float* b_hh = (const float*)d_in[5];
    const float* W1   = (const float*)d_in[6];
    const float* b1   = (const float*)d_in[7];
    const float* W2   = (const float*)d_in[8];
    const float* b2   = (const float*)d_in[9];
    const float* W3   = (const float*)d_in[10];
    const float* b3   = (const float*)d_in[11];
    float* out = (float*)d_out;

    float* ws = (float*)d_ws;
    ushort* ebf  = (ushort*)ws;                     // 6,553,600 ush
    ushort* Xgh  = (ushort*)(ws + 3276800);         // 26,214,400 ush (fp16 Xg)
    float* bsum  = ws + 3276800 + 13107200;         // 1024
    float* hN    = bsum + 1024;                     // 65,536
    float* cN    = hN + 65536;                      // 65,536
    ushort* hNb  = (ushort*)(cN + 65536);           // 65,536 ush
    float* hhdec = cN + 65536 + 32768;              // 262,144
    uint*  WPu   = (uint*)(hhdec + 262144);         // 131,072 uints
    ushort* Wihb = (ushort*)(WPu + 131072);         // 131,072 ush
    ushort* Whhb = Wihb + 131072;                   // 262,144 ush
    ushort* W1T  = Whhb + 262144;                   // 131,072 ush
    ushort* W2T  = W1T + 131072;                    // 65,536 ush
    // reuse (stream-ordered):
    ushort* Gdecb   = Xgh;                          // decoder gates bf16
    ushort* hdec_bf = ebf;                          // after Gdec GEMM, ebf dead
    ushort* z1b     = Xgh;                          // after dec_cell, Gdecb dead

    k_bsum<<<4, 256, 0, stream>>>(b_ih, b_hh, bsum);
    k_prep_wp<<<dim3(8, 32), 256, 0, stream>>>(W_hh, WPu);
    k_tr_bf16<<<dim3(16, 8),  256, 0, stream>>>(W1, W1T, H_, P1_);
    k_tr_bf16<<<dim3(4, 16),  256, 0, stream>>>(W2, W2T, P1_, P2_);
    k_cvt_bf16<<<512, 256, 0, stream>>>(W_ih, Wihb, G4 * E_);
    k_cvt_bf16<<<1024, 256, 0, stream>>>(W_hh, Whhb, G4 * H_);
    k_gather<<<B_ * S_ / 2, 256, 0, stream>>>(x, emb, ebf);

    // Xg = e_hist @ W_ih^T + bsum  -> fp16 (feeds the scan)
    k_gemm_mfma<0, 2><<<dim3(G4 / 128, (B_ * T_) / 128), 256, 0, stream>>>(
        ebf, T_, (long)S_ * E_, (long)E_, Wihb, bsum, nullptr, 1,
        Xgh, G4, E_);

    // persistent scan: W fully resident; thread-local cell update
    size_t scan_smem = (size_t)1024 * LDW3 * 4 + 128 * sizeof(uint);
    k_lstm_scan<<<B_, 256, scan_smem, stream>>>(Xgh, WPu, hN, cN, hNb);

    // hhdec = hN @ W_hh^T + bsum  (MFMA, M=256)
    k_gemm_mfma<0, 0><<<dim3(G4 / 128, B_ / 128), 256, 0, stream>>>(
        hNb, B_, 0L, (long)H_, Whhb, bsum, nullptr, 1,
        hhdec, G4, H_);

    // Gdec = e_tgt @ W_ih^T + hhdec[b]  (bf16 out; decoder is non-recurrent)
    k_gemm_mfma<0, 1><<<dim3(G4 / 128, (B_ * T_) / 128), 256, 0, stream>>>(
        ebf + T_ * E_, T_, (long)S_ * E_, (long)E_, Wihb, nullptr, hhdec, T_,
        Gdecb, G4, E_);

    // decode cell (bf16 in) -> hdec_bf
    k_dec_cell<<<(B_ * T_ * H_) / 256, 256, 0, stream>>>(Gdecb, cN, hdec_bf);

    // z1 = relu(hdec @ W1 + b1) -> bf16
    k_gemm_mfma<1, 1><<<dim3(P1_ / 128, (B_ * T_) / 128), 256, 0, stream>>>(
        hdec_bf, B_ * T_, 0L, (long)H_, W1T, b1, nullptr, 1,
        z1b, P1_, H_);

    // z2 GEMM + mlp3 fused -> out
    k_z2_fused<<<(B_ * T_) / 128, 256, 0, stream>>>(z1b, W2T, b2, W3, b3, out);
}

// Round 15
// 406.107 us; speedup vs baseline: 6.7016x; 6.7016x over previous
//
#include <hip/hip_runtime.h>
#include <hip/hip_bf16.h>
#include <math.h>

#define B_  256
#define S_  200
#define F_  10
#define T_  100
#define E_  128
#define H_  256
#define G4  1024   // 4*H
#define P1_ 512
#define P2_ 128

typedef __attribute__((ext_vector_type(8))) short short8;
typedef __attribute__((ext_vector_type(4))) float f32x4;
typedef _Float16 half2f __attribute__((ext_vector_type(2)));

#if __has_builtin(__builtin_amdgcn_fdot2)
#define FDOT2(w2, h2, acc) __builtin_amdgcn_fdot2((w2), (h2), (acc), false)
#else
#define FDOT2(w2, h2, acc) ((acc) + (float)((w2)[0]) * (float)((h2)[0]) + (float)((w2)[1]) * (float)((h2)[1]))
#endif
#define BCH2(u) __builtin_bit_cast(half2f, (u))

// scan W placement (kpair rows of 1024 uints): 36 in LDS, 92 in VGPRs (x2 cols)
// HARD CONSTRAINT (r14 lesson): arch VGPR cap is 256/thread. 92*2=184 + ~40 fits.
#define NL2_ 36
#define NV2_ 92

__device__ __forceinline__ float sigf(float x) { return 1.0f / (1.0f + expf(-x)); }
__device__ __forceinline__ float bf2f(ushort u) { return __uint_as_float(((uint)u) << 16); }
__device__ __forceinline__ ushort f2bf(float f) {
    __hip_bfloat16 v = __float2bfloat16(f);
    return *(ushort*)&v;
}
__device__ __forceinline__ ushort f2h(float f) {
    _Float16 h = (_Float16)f;
    return __builtin_bit_cast(ushort, h);
}
__device__ __forceinline__ float h2f(ushort u) {
    return (float)__builtin_bit_cast(_Float16, u);
}

__global__ __launch_bounds__(256) void k_bsum(const float* __restrict__ bi,
                                              const float* __restrict__ bh,
                                              float* __restrict__ bs) {
    int i = blockIdx.x * 256 + threadIdx.x;
    if (i < G4) bs[i] = bi[i] + bh[i];
}

// W (R x C) f32 -> WT (C x R) bf16. grid (C/32, R/32), 256 thr.
__global__ __launch_bounds__(256) void k_tr_bf16(const float* __restrict__ W,
                                                 ushort* __restrict__ WT,
                                                 int R, int C) {
    __shared__ float t[32][33];
    int c0 = blockIdx.x * 32, r0 = blockIdx.y * 32;
    int lc = threadIdx.x & 31, lr = threadIdx.x >> 5;
    #pragma unroll
    for (int i = 0; i < 4; ++i)
        t[lr + 8 * i][lc] = W[(long)(r0 + lr + 8 * i) * C + c0 + lc];
    __syncthreads();
    #pragma unroll
    for (int i = 0; i < 4; ++i)
        WT[(long)(c0 + lr + 8 * i) * R + r0 + lc] = f2bf(t[lc][lr + 8 * i]);
}

// W_hh (1024 x 256) f32 -> WPu: k-pair-interleaved fp16.
__global__ __launch_bounds__(256) void k_prep_wp(const float* __restrict__ W,
                                                 uint* __restrict__ WPu) {
    __shared__ float t[32][33];
    int k0 = blockIdx.x * 32, c0 = blockIdx.y * 32;
    int lk = threadIdx.x & 31, lc8 = threadIdx.x >> 5;
    #pragma unroll
    for (int i = 0; i < 4; ++i)
        t[lc8 + 8 * i][lk] = W[(long)(c0 + lc8 + 8 * i) * 256 + k0 + lk];
    __syncthreads();
    int kpl = threadIdx.x >> 4;
    int ccl = threadIdx.x & 15;
    #pragma unroll
    for (int hf = 0; hf < 2; ++hf) {
        int c = ccl + 16 * hf;
        uint lo = f2h(t[c][2 * kpl]);
        uint hi = f2h(t[c][2 * kpl + 1]);
        WPu[(long)(k0 / 2 + kpl) * G4 + c0 + c] = lo | (hi << 16);
    }
}

__global__ __launch_bounds__(256) void k_cvt_bf16(const float* __restrict__ W,
                                                  ushort* __restrict__ O, int n) {
    int i = blockIdx.x * 256 + threadIdx.x;
    if (i < n) O[i] = f2bf(W[i]);
}

// two (b,s) rows per block; 256 threads; bf16 out
__global__ __launch_bounds__(256) void k_gather(const int* __restrict__ x,
                                                const float* __restrict__ emb,
                                                ushort* __restrict__ e) {
    int bs = blockIdx.x * 2 + (threadIdx.x >> 7);
    int t  = threadIdx.x & 127;
    const int* xr = x + (long)bs * F_;
    float acc = 0.f;
    #pragma unroll
    for (int f = 0; f < F_; ++f) acc += emb[(long)xr[f] * E_ + t];
    e[(long)bs * E_ + t] = f2bf(acc * (1.0f / F_));
}

// ---------------- bf16 MFMA GEMM. OUTM: 0=f32, 1=bf16, 2=f16 ----------------
template<int ACT, int OUTM>
__global__ __launch_bounds__(256) void k_gemm_mfma(
    const ushort* __restrict__ A, int rowDiv, long sOuter, long sInner,
    const ushort* __restrict__ Bm,
    const float* __restrict__ bias,
    const float* __restrict__ rowAdd, int rowAddDiv,
    void* __restrict__ Cout, int N, int K)
{
    constexpr int LDT = 40;
    __shared__ ushort Al[128 * LDT];
    __shared__ ushort Bl[128 * LDT];
    int tid = threadIdx.x;
    int n0 = blockIdx.x * 128;
    int m0 = blockIdx.y * 128;

    int rA = tid >> 2, qA = tid & 3;
    int m_lo = m0 + rA, m_hi = m_lo + 64;
    long a0 = (long)(m_lo / rowDiv) * sOuter + (long)(m_lo % rowDiv) * sInner + qA * 8;
    long a1 = (long)(m_hi / rowDiv) * sOuter + (long)(m_hi % rowDiv) * sInner + qA * 8;
    const ushort* b0p = Bm + (long)(n0 + rA) * K + qA * 8;
    const ushort* b1p = Bm + (long)(n0 + rA + 64) * K + qA * 8;

    int lane = tid & 63, wave = tid >> 6;
    int wr = wave >> 1, wc = wave & 1;
    int lrow = lane & 15, lkh = lane >> 4;

    const f32x4 fz = {0.f, 0.f, 0.f, 0.f};
    f32x4 acc[4][4];
    #pragma unroll
    for (int i = 0; i < 4; ++i)
        #pragma unroll
        for (int j = 0; j < 4; ++j) acc[i][j] = fz;

    int nk = K >> 5;
    for (int kc = 0; kc < nk; ++kc) {
        uint4 va0 = *(const uint4*)(A + a0 + kc * 32);
        uint4 va1 = *(const uint4*)(A + a1 + kc * 32);
        uint4 vb0 = *(const uint4*)(b0p + kc * 32);
        uint4 vb1 = *(const uint4*)(b1p + kc * 32);
        *(uint4*)&Al[rA * LDT + qA * 8]        = va0;
        *(uint4*)&Al[(rA + 64) * LDT + qA * 8] = va1;
        *(uint4*)&Bl[rA * LDT + qA * 8]        = vb0;
        *(uint4*)&Bl[(rA + 64) * LDT + qA * 8] = vb1;
        __syncthreads();
        short8 af[4], bfr[4];
        #pragma unroll
        for (int mi = 0; mi < 4; ++mi)
            af[mi] = *(const short8*)&Al[(wr * 64 + mi * 16 + lrow) * LDT + lkh * 8];
        #pragma unroll
        for (int ni = 0; ni < 4; ++ni)
            bfr[ni] = *(const short8*)&Bl[(wc * 64 + ni * 16 + lrow) * LDT + lkh * 8];
        #pragma unroll
        for (int mi = 0; mi < 4; ++mi)
            #pragma unroll
            for (int ni = 0; ni < 4; ++ni)
                acc[mi][ni] = __builtin_amdgcn_mfma_f32_16x16x32_bf16(
                    af[mi], bfr[ni], acc[mi][ni], 0, 0, 0);
        __syncthreads();
    }
    #pragma unroll
    for (int mi = 0; mi < 4; ++mi) {
        #pragma unroll
        for (int r = 0; r < 4; ++r) {
            int m = m0 + wr * 64 + mi * 16 + lkh * 4 + r;
            long rowoff = rowAdd ? (long)(m / rowAddDiv) * N : 0;
            #pragma unroll
            for (int ni = 0; ni < 4; ++ni) {
                int n = n0 + wc * 64 + ni * 16 + lrow;
                float v = acc[mi][ni][r];
                if (bias)   v += bias[n];
                if (rowAdd) v += rowAdd[rowoff + n];
                if (ACT)    v = fmaxf(v, 0.f);
                if (OUTM == 1)      ((ushort*)Cout)[(long)m * N + n] = f2bf(v);
                else if (OUTM == 2) ((ushort*)Cout)[(long)m * N + n] = f2h(v);
                else                ((float*)Cout)[(long)m * N + n] = v;
            }
        }
    }
}

// ---------------- fused Gdec GEMM + decode cell ----------------
// Block computes ALL FOUR gate panels for cells [j0, j0+32) x 128 m-rows:
// tile col n -> W_ih row (n>>5)*256 + j0 + (n&31). After the K-loop the
// gates (+hhdec rowAdd) are staged bf16 in LDS and the LSTM cell is applied
// in-block; hdec (bf16) is the only global output. Gdec never touches HBM.
__global__ __launch_bounds__(256) void k_gdec_fused(
    const ushort* __restrict__ A, int rowDiv, long sOuter, long sInner,
    const ushort* __restrict__ Bm,      // Wihb (1024 x 128) bf16 (N,K)
    const float* __restrict__ hhdec,    // [B][1024]
    const float* __restrict__ cNb,      // [B][256]
    ushort* __restrict__ hdec)          // [B*T][256] bf16
{
    constexpr int LDT = 40;
    __shared__ ushort Al[128 * LDT];
    __shared__ ushort Bl[128 * LDT];
    __shared__ ushort Zl[128 * 132];    // gates tile, bf16
    int tid = threadIdx.x;
    int j0 = blockIdx.x * 32;
    int m0 = blockIdx.y * 128;
    const int K = E_;

    int rA = tid >> 2, qA = tid & 3;
    int m_lo = m0 + rA, m_hi = m_lo + 64;
    long a0 = (long)(m_lo / rowDiv) * sOuter + (long)(m_lo % rowDiv) * sInner + qA * 8;
    long a1 = (long)(m_hi / rowDiv) * sOuter + (long)(m_hi % rowDiv) * sInner + qA * 8;
    int nr0 = rA, nr1 = rA + 64;
    const ushort* b0p = Bm + (long)((nr0 >> 5) * 256 + j0 + (nr0 & 31)) * K + qA * 8;
    const ushort* b1p = Bm + (long)((nr1 >> 5) * 256 + j0 + (nr1 & 31)) * K + qA * 8;

    int lane = tid & 63, wave = tid >> 6;
    int wr = wave >> 1, wc = wave & 1;
    int lrow = lane & 15, lkh = lane >> 4;

    const f32x4 fz = {0.f, 0.f, 0.f, 0.f};
    f32x4 acc[4][4];
    #pragma unroll
    for (int i = 0; i < 4; ++i)
        #pragma unroll
        for (int j = 0; j < 4; ++j) acc[i][j] = fz;

    for (int kc = 0; kc < K / 32; ++kc) {
        uint4 va0 = *(const uint4*)(A + a0 + kc * 32);
        uint4 va1 = *(const uint4*)(A + a1 + kc * 32);
        uint4 vb0 = *(const uint4*)(b0p + kc * 32);
        uint4 vb1 = *(const uint4*)(b1p + kc * 32);
        *(uint4*)&Al[rA * LDT + qA * 8]        = va0;
        *(uint4*)&Al[(rA + 64) * LDT + qA * 8] = va1;
        *(uint4*)&Bl[rA * LDT + qA * 8]        = vb0;
        *(uint4*)&Bl[(rA + 64) * LDT + qA * 8] = vb1;
        __syncthreads();
        short8 af[4], bfr[4];
        #pragma unroll
        for (int mi = 0; mi < 4; ++mi)
            af[mi] = *(const short8*)&Al[(wr * 64 + mi * 16 + lrow) * LDT + lkh * 8];
        #pragma unroll
        for (int ni = 0; ni < 4; ++ni)
            bfr[ni] = *(const short8*)&Bl[(wc * 64 + ni * 16 + lrow) * LDT + lkh * 8];
        #pragma unroll
        for (int mi = 0; mi < 4; ++mi)
            #pragma unroll
            for (int ni = 0; ni < 4; ++ni)
                acc[mi][ni] = __builtin_amdgcn_mfma_f32_16x16x32_bf16(
                    af[mi], bfr[ni], acc[mi][ni], 0, 0, 0);
        __syncthreads();
    }
    // stage gates (+ hhdec rowAdd) as bf16
    #pragma unroll
    for (int mi = 0; mi < 4; ++mi) {
        #pragma unroll
        for (int r = 0; r < 4; ++r) {
            int row = wr * 64 + mi * 16 + lkh * 4 + r;
            int bidx = (m0 + row) / T_;
            #pragma unroll
            for (int ni = 0; ni < 4; ++ni) {
                int col = wc * 64 + ni * 16 + lrow;
                float v = acc[mi][ni][r]
                        + hhdec[(long)bidx * G4 + (col >> 5) * 256 + j0 + (col & 31)];
                Zl[row * 132 + col] = f2bf(v);
            }
        }
    }
    __syncthreads();
    // cell epilogue: thread -> jl = tid&31, m-rows mb*16..mb*16+15
    int jl = tid & 31, mb = tid >> 5;
    #pragma unroll
    for (int q = 0; q < 16; ++q) {
        int row = mb * 16 + q;
        int m = m0 + row;
        int bidx = m / T_;
        float gi = bf2f(Zl[row * 132 +      jl]);
        float gf = bf2f(Zl[row * 132 + 32 + jl]);
        float gg = bf2f(Zl[row * 132 + 64 + jl]);
        float go = bf2f(Zl[row * 132 + 96 + jl]);
        float cv = sigf(gf) * cNb[(long)bidx * H_ + j0 + jl] + sigf(gi) * tanhf(gg);
        hdec[(long)m * H_ + j0 + jl] = f2bf(sigf(go) * tanhf(cv));
    }
}

// ---------------- z2 GEMM with fused mlp3 epilogue ----------------
__global__ __launch_bounds__(256) void k_z2_fused(
    const ushort* __restrict__ A, const ushort* __restrict__ Bm,
    const float* __restrict__ b2, const float* __restrict__ W3,
    const float* __restrict__ b3, float* __restrict__ out)
{
    constexpr int LDT = 40;
    __shared__ ushort Al[128 * LDT];
    __shared__ ushort Bl[128 * LDT];
    __shared__ float Zl[128 * 132];
    int tid = threadIdx.x;
    int m0 = blockIdx.x * 128;
    const int K = P1_;

    int rA = tid >> 2, qA = tid & 3;
    const ushort* a0p = A + (long)(m0 + rA) * K + qA * 8;
    const ushort* a1p = A + (long)(m0 + rA + 64) * K + qA * 8;
    const ushort* b0p = Bm + (long)rA * K + qA * 8;
    const ushort* b1p = Bm + (long)(rA + 64) * K + qA * 8;

    int lane = tid & 63, wave = tid >> 6;
    int wr = wave >> 1, wc = wave & 1;
    int lrow = lane & 15, lkh = lane >> 4;

    const f32x4 fz = {0.f, 0.f, 0.f, 0.f};
    f32x4 acc[4][4];
    #pragma unroll
    for (int i = 0; i < 4; ++i)
        #pragma unroll
        for (int j = 0; j < 4; ++j) acc[i][j] = fz;

    for (int kc = 0; kc < K / 32; ++kc) {
        uint4 va0 = *(const uint4*)(a0p + kc * 32);
        uint4 va1 = *(const uint4*)(a1p + kc * 32);
        uint4 vb0 = *(const uint4*)(b0p + kc * 32);
        uint4 vb1 = *(const uint4*)(b1p + kc * 32);
        *(uint4*)&Al[rA * LDT + qA * 8]        = va0;
        *(uint4*)&Al[(rA + 64) * LDT + qA * 8] = va1;
        *(uint4*)&Bl[rA * LDT + qA * 8]        = vb0;
        *(uint4*)&Bl[(rA + 64) * LDT + qA * 8] = vb1;
        __syncthreads();
        short8 af[4], bfr[4];
        #pragma unroll
        for (int mi = 0; mi < 4; ++mi)
            af[mi] = *(const short8*)&Al[(wr * 64 + mi * 16 + lrow) * LDT + lkh * 8];
        #pragma unroll
        for (int ni = 0; ni < 4; ++ni)
            bfr[ni] = *(const short8*)&Bl[(wc * 64 + ni * 16 + lrow) * LDT + lkh * 8];
        #pragma unroll
        for (int mi = 0; mi < 4; ++mi)
            #pragma unroll
            for (int ni = 0; ni < 4; ++ni)
                acc[mi][ni] = __builtin_amdgcn_mfma_f32_16x16x32_bf16(
                    af[mi], bfr[ni], acc[mi][ni], 0, 0, 0);
        __syncthreads();
    }
    #pragma unroll
    for (int mi = 0; mi < 4; ++mi) {
        #pragma unroll
        for (int r = 0; r < 4; ++r) {
            int row = wr * 64 + mi * 16 + lkh * 4 + r;
            #pragma unroll
            for (int ni = 0; ni < 4; ++ni) {
                int col = wc * 64 + ni * 16 + lrow;
                Zl[row * 132 + col] = fmaxf(acc[mi][ni][r] + b2[col], 0.f);
            }
        }
    }
    __syncthreads();
    float w3a = W3[lane], w3b = W3[64 + lane], b3v = b3[0];
    for (int r = 0; r < 32; ++r) {
        int row = wave * 32 + r;
        float s = Zl[row * 132 + lane] * w3a + Zl[row * 132 + 64 + lane] * w3b;
        #pragma unroll
        for (int off = 32; off > 0; off >>= 1) s += __shfl_down(s, off);
        if (lane == 0) out[m0 + row] = sigf(s + b3v);
    }
}

// Persistent LSTM scan, W fully CU-resident (r13-verified, 204 us). 512
// threads/block, 2 waves/SIMD; each thread owns cols (tid, tid+512).
// W rows 0..NL2_-1 in LDS transposed [col][row]; rows NL2_..127 in VGPRs.
__global__ __launch_bounds__(512, 2) void k_lstm_scan(
    const ushort* __restrict__ Xgh, const uint* __restrict__ WPu,
    float* __restrict__ hN, float* __restrict__ cN, ushort* __restrict__ hNb)
{
    extern __shared__ __align__(16) char smem[];
    uint*   Wl    = (uint*)smem;                    // [1024 cols][NL2_ rows]
    float*  act_s = (float*)(smem + NL2_ * 4096);   // 1024 f32
    uint*   h16u  = (uint*)(act_s + G4);            // 128 uints (packed f16 h)
    ushort* h16   = (ushort*)h16u;
    int tid = threadIdx.x;
    int b   = blockIdx.x;
    int cB  = tid + 512;

    for (int i = tid; i < NL2_ * 1024; i += 512) {
        int row = i >> 10, col = i & 1023;
        Wl[col * NL2_ + row] = WPu[(long)row * G4 + col];
    }
    uint wrA[NV2_], wrB[NV2_];
    #pragma unroll
    for (int i = 0; i < NV2_; ++i) {
        wrA[i] = WPu[(long)(NL2_ + i) * G4 + tid];
        wrB[i] = WPu[(long)(NL2_ + i) * G4 + cB];
    }
    if (tid < 128) h16u[tid] = 0;
    float c_r = 0.f;
    __syncthreads();

    int isTanhB = (tid >> 8) == 0;
    const ushort* xgp = Xgh + (long)b * T_ * G4;
    const uint* wcA = Wl + tid * NL2_;
    const uint* wcB = Wl + (tid + 512) * NL2_;

    for (int t = 0; t < T_; ++t) {
        float xvA = h2f(xgp[(long)t * G4 + tid]);
        float xvB = h2f(xgp[(long)t * G4 + cB]);
        float aA0 = 0.f, aA1 = 0.f, aB0 = 0.f, aB1 = 0.f;
        #pragma unroll
        for (int r4 = 0; r4 < NL2_ / 4; ++r4) {
            uint4 hh = *(const uint4*)(h16u + 4 * r4);
            uint4 wa = *(const uint4*)(wcA + 4 * r4);
            uint4 wb = *(const uint4*)(wcB + 4 * r4);
            aA0 = FDOT2(BCH2(wa.x), BCH2(hh.x), aA0); aB0 = FDOT2(BCH2(wb.x), BCH2(hh.x), aB0);
            aA1 = FDOT2(BCH2(wa.y), BCH2(hh.y), aA1); aB1 = FDOT2(BCH2(wb.y), BCH2(hh.y), aB1);
            aA0 = FDOT2(BCH2(wa.z), BCH2(hh.z), aA0); aB0 = FDOT2(BCH2(wb.z), BCH2(hh.z), aB0);
            aA1 = FDOT2(BCH2(wa.w), BCH2(hh.w), aA1); aB1 = FDOT2(BCH2(wb.w), BCH2(hh.w), aB1);
        }
        #pragma unroll
        for (int r4 = 0; r4 < NV2_ / 4; ++r4) {
            uint4 hh = *(const uint4*)(h16u + NL2_ + 4 * r4);
            aA0 = FDOT2(BCH2(wrA[4 * r4 + 0]), BCH2(hh.x), aA0);
            aB0 = FDOT2(BCH2(wrB[4 * r4 + 0]), BCH2(hh.x), aB0);
            aA1 = FDOT2(BCH2(wrA[4 * r4 + 1]), BCH2(hh.y), aA1);
            aB1 = FDOT2(BCH2(wrB[4 * r4 + 1]), BCH2(hh.y), aB1);
            aA0 = FDOT2(BCH2(wrA[4 * r4 + 2]), BCH2(hh.z), aA0);
            aB0 = FDOT2(BCH2(wrB[4 * r4 + 2]), BCH2(hh.z), aB0);
            aA1 = FDOT2(BCH2(wrA[4 * r4 + 3]), BCH2(hh.w), aA1);
            aB1 = FDOT2(BCH2(wrB[4 * r4 + 3]), BCH2(hh.w), aB1);
        }
        float aA = aA0 + aA1, aB = aB0 + aB1;
        act_s[tid] = sigf(aA + xvA);
        float gB = aB + xvB;
        act_s[cB] = isTanhB ? tanhf(gB) : sigf(gB);
        __syncthreads();
        if (tid < H_) {
            float cn = act_s[H_ + tid] * c_r + act_s[tid] * act_s[2 * H_ + tid];
            c_r = cn;
            float h = act_s[3 * H_ + tid] * tanhf(cn);
            h16[tid] = f2h(h);
            if (t == T_ - 1) {
                hN[(long)b * H_ + tid] = h;
                cN[(long)b * H_ + tid] = c_r;
                hNb[(long)b * H_ + tid] = f2bf(h);
            }
        }
        __syncthreads();
    }
}

extern "C" void kernel_launch(void* const* d_in, const int* in_sizes, int n_in,
                              void* d_out, int out_size, void* d_ws, size_t ws_size,
                              hipStream_t stream)
{
    const int*   x    = (const int*)d_in[0];
    const float* emb  = (const float*)d_in[1];
    const float* W_ih = (const float*)d_in[2];
    const float* W_hh = (const float*)d_in[3];
    const float* b_ih = (const float*)d_in[4];
    const float* b_hh = (const float*)d_in[5];
    const float* W1   = (const float*)d_in[6];
    const float* b1   = (const float*)d_in[7];
    const float* W2   = (const float*)d_in[8];
    const float* b2   = (const float*)d_in[9];
    const float* W3   = (const float*)d_in[10];
    const float* b3   = (const float*)d_in[11];
    float* out = (float*)d_out;

    float* ws = (float*)d_ws;
    ushort* ebf   = (ushort*)ws;                    // 6,553,600 ush
    ushort* Xgh   = (ushort*)(ws + 3276800);        // 26,214,400 ush (fp16 Xg)
    ushort* hdecb = (ushort*)(ws + 16384000);       // 6,553,600 ush
    ushort* z1b   = (ushort*)(ws + 19660800);       // 13,107,200 ush
    float* bsum  = ws + 26214400;                   // 1024
    float* hN    = bsum + 1024;                     // 65,536
    float* cN    = hN + 65536;                      // 65,536
    ushort* hNb  = (ushort*)(cN + 65536);           // 65,536 ush
    float* hhdec = cN + 65536 + 32768;              // 262,144
    uint*  WPu   = (uint*)(hhdec + 262144);         // 131,072 uints
    ushort* Wihb = (ushort*)(WPu + 131072);         // 131,072 ush
    ushort* Whhb = Wihb + 131072;                   // 262,144 ush
    ushort* W1T  = Whhb + 262144;                   // 131,072 ush
    ushort* W2T  = W1T + 131072;                    // 65,536 ush

    k_bsum<<<4, 256, 0, stream>>>(b_ih, b_hh, bsum);
    k_prep_wp<<<dim3(8, 32), 256, 0, stream>>>(W_hh, WPu);
    k_tr_bf16<<<dim3(16, 8),  256, 0, stream>>>(W1, W1T, H_, P1_);
    k_tr_bf16<<<dim3(4, 16),  256, 0, stream>>>(W2, W2T, P1_, P2_);
    k_cvt_bf16<<<512, 256, 0, stream>>>(W_ih, Wihb, G4 * E_);
    k_cvt_bf16<<<1024, 256, 0, stream>>>(W_hh, Whhb, G4 * H_);
    k_gather<<<B_ * S_ / 2, 256, 0, stream>>>(x, emb, ebf);

    // Xg = e_hist @ W_ih^T + bsum  -> fp16 (feeds the scan)
    k_gemm_mfma<0, 2><<<dim3(G4 / 128, (B_ * T_) / 128), 256, 0, stream>>>(
        ebf, T_, (long)S_ * E_, (long)E_, Wihb, bsum, nullptr, 1,
        Xgh, G4, E_);

    // persistent scan: W fully resident; writes hN (f32), cN, hNb (bf16)
    size_t scan_smem = (size_t)NL2_ * 4096 + G4 * sizeof(float) + 128 * sizeof(uint);
    k_lstm_scan<<<B_, 512, scan_smem, stream>>>(Xgh, WPu, hN, cN, hNb);

    // hhdec = hN @ W_hh^T + bsum  (MFMA, M=256)
    k_gemm_mfma<0, 0><<<dim3(G4 / 128, B_ / 128), 256, 0, stream>>>(
        hNb, B_, 0L, (long)H_, Whhb, bsum, nullptr, 1,
        hhdec, G4, H_);

    // fused Gdec GEMM + decode cell -> hdecb (Gdec gates never hit HBM)
    k_gdec_fused<<<dim3(H_ / 32, (B_ * T_) / 128), 256, 0, stream>>>(
        ebf + T_ * E_, T_, (long)S_ * E_, (long)E_, Wihb, hhdec, cN, hdecb);

    // z1 = relu(hdec @ W1 + b1) -> bf16
    k_gemm_mfma<1, 1><<<dim3(P1_ / 128, (B_ * T_) / 128), 256, 0, stream>>>(
        hdecb, B_ * T_, 0L, (long)H_, W1T, b1, nullptr, 1,
        z1b, P1_, H_);

    // z2 GEMM + mlp3 fused -> out
    k_z2_fused<<<(B_ * T_) / 128, 256, 0, stream>>>(z1b, W2T, b2, W3, b3, out);
}

// Round 16
// 378.478 us; speedup vs baseline: 7.1908x; 1.0730x over previous
//
#include <hip/hip_runtime.h>
#include <hip/hip_bf16.h>
#include <math.h>

#define B_  256
#define S_  200
#define F_  10
#define T_  100
#define E_  128
#define H_  256
#define G4  1024   // 4*H
#define P1_ 512
#define P2_ 128

typedef __attribute__((ext_vector_type(8))) short short8;
typedef __attribute__((ext_vector_type(4))) float f32x4;
typedef _Float16 half2f __attribute__((ext_vector_type(2)));

#if __has_builtin(__builtin_amdgcn_fdot2)
#define FDOT2(w2, h2, acc) __builtin_amdgcn_fdot2((w2), (h2), (acc), false)
#else
#define FDOT2(w2, h2, acc) ((acc) + (float)((w2)[0]) * (float)((h2)[0]) + (float)((w2)[1]) * (float)((h2)[1]))
#endif
#define BCH2(u) __builtin_bit_cast(half2f, (u))

// scan W placement (kpair rows of 1024 uints): 36 in LDS, 92 in VGPRs (x2 cols)
// HARD CONSTRAINT (r14 lesson): arch VGPR cap is 256/thread. 92*2=184 + ~40 fits.
#define NL2_ 36
#define NV2_ 92

__device__ __forceinline__ float fsig(float x) { return 1.0f / (1.0f + __expf(-x)); }
__device__ __forceinline__ float ftanh(float x) { return 1.0f - 2.0f / (__expf(2.0f * x) + 1.0f); }
__device__ __forceinline__ float bf2f(ushort u) { return __uint_as_float(((uint)u) << 16); }
__device__ __forceinline__ ushort f2bf(float f) {
    __hip_bfloat16 v = __float2bfloat16(f);
    return *(ushort*)&v;
}
__device__ __forceinline__ ushort f2h(float f) {
    _Float16 h = (_Float16)f;
    return __builtin_bit_cast(ushort, h);
}
__device__ __forceinline__ float h2f(ushort u) {
    return (float)__builtin_bit_cast(_Float16, u);
}

// ---------------- mega prep kernel: all independent prep work, 1 launch ----
// blocks [0,256): W_hh -> WPu (fp16 kpair-interleaved)
// blocks [256,384): W1 -> W1T bf16 transpose (R=256,C=512)
// blocks [384,448): W2 -> W2T bf16 transpose (R=512,C=128)
// blocks [448,960): W_ih -> Wihb bf16 cvt
// blocks [960,1984): W_hh -> Whhb bf16 cvt
// blocks [1984,1988): bsum
// blocks [1988,...): gather (2 rows/block)
__global__ __launch_bounds__(256) void k_prep_all(
    const float* __restrict__ W_hh, uint* __restrict__ WPu,
    const float* __restrict__ W1, ushort* __restrict__ W1T,
    const float* __restrict__ W2, ushort* __restrict__ W2T,
    const float* __restrict__ W_ih, ushort* __restrict__ Wihb,
    ushort* __restrict__ Whhb,
    const float* __restrict__ b_ih, const float* __restrict__ b_hh,
    float* __restrict__ bsum,
    const int* __restrict__ x, const float* __restrict__ emb,
    ushort* __restrict__ ebf)
{
    __shared__ float t[32][33];
    int blk = blockIdx.x;
    int tid = threadIdx.x;
    if (blk < 256) {                       // prep_wp
        int k0 = (blk & 7) * 32, c0 = (blk >> 3) * 32;
        int lk = tid & 31, lc8 = tid >> 5;
        #pragma unroll
        for (int i = 0; i < 4; ++i)
            t[lc8 + 8 * i][lk] = W_hh[(long)(c0 + lc8 + 8 * i) * 256 + k0 + lk];
        __syncthreads();
        int kpl = tid >> 4, ccl = tid & 15;
        #pragma unroll
        for (int hf = 0; hf < 2; ++hf) {
            int c = ccl + 16 * hf;
            uint lo = f2h(t[c][2 * kpl]);
            uint hi = f2h(t[c][2 * kpl + 1]);
            WPu[(long)(k0 / 2 + kpl) * G4 + c0 + c] = lo | (hi << 16);
        }
    } else if (blk < 448) {                // transposes
        const float* W; ushort* WT; int R, C, idx;
        if (blk < 384) { W = W1; WT = W1T; R = H_;  C = P1_; idx = blk - 256;
                         idx = (idx & 15) | ((idx >> 4) << 8); }
        else           { W = W2; WT = W2T; R = P1_; C = P2_; idx = blk - 384;
                         idx = (idx & 3) | ((idx >> 2) << 8); }
        int c0 = (idx & 255) * 32, r0 = (idx >> 8) * 32;
        int lc = tid & 31, lr = tid >> 5;
        #pragma unroll
        for (int i = 0; i < 4; ++i)
            t[lr + 8 * i][lc] = W[(long)(r0 + lr + 8 * i) * C + c0 + lc];
        __syncthreads();
        #pragma unroll
        for (int i = 0; i < 4; ++i)
            WT[(long)(c0 + lr + 8 * i) * R + r0 + lc] = f2bf(t[lc][lr + 8 * i]);
    } else if (blk < 960) {                // cvt W_ih
        int i = (blk - 448) * 256 + tid;
        Wihb[i] = f2bf(W_ih[i]);
    } else if (blk < 1984) {               // cvt W_hh
        int i = (blk - 960) * 256 + tid;
        Whhb[i] = f2bf(W_hh[i]);
    } else if (blk < 1988) {               // bsum
        int i = (blk - 1984) * 256 + tid;
        bsum[i] = b_ih[i] + b_hh[i];
    } else {                               // gather
        int bs = (blk - 1988) * 2 + (tid >> 7);
        int e  = tid & 127;
        const int* xr = x + (long)bs * F_;
        float acc = 0.f;
        #pragma unroll
        for (int f = 0; f < F_; ++f) acc += emb[(long)xr[f] * E_ + e];
        ebf[(long)bs * E_ + e] = f2bf(acc * (1.0f / F_));
    }
}

// ---------------- bf16 MFMA GEMM. OUTM: 0=f32, 1=bf16, 2=f16 ----------------
template<int ACT, int OUTM>
__global__ __launch_bounds__(256) void k_gemm_mfma(
    const ushort* __restrict__ A, int rowDiv, long sOuter, long sInner,
    const ushort* __restrict__ Bm,
    const float* __restrict__ bias,
    const float* __restrict__ rowAdd, int rowAddDiv,
    void* __restrict__ Cout, int N, int K)
{
    constexpr int LDT = 40;
    __shared__ ushort Al[128 * LDT];
    __shared__ ushort Bl[128 * LDT];
    int tid = threadIdx.x;
    int n0 = blockIdx.x * 128;
    int m0 = blockIdx.y * 128;

    int rA = tid >> 2, qA = tid & 3;
    int m_lo = m0 + rA, m_hi = m_lo + 64;
    long a0 = (long)(m_lo / rowDiv) * sOuter + (long)(m_lo % rowDiv) * sInner + qA * 8;
    long a1 = (long)(m_hi / rowDiv) * sOuter + (long)(m_hi % rowDiv) * sInner + qA * 8;
    const ushort* b0p = Bm + (long)(n0 + rA) * K + qA * 8;
    const ushort* b1p = Bm + (long)(n0 + rA + 64) * K + qA * 8;

    int lane = tid & 63, wave = tid >> 6;
    int wr = wave >> 1, wc = wave & 1;
    int lrow = lane & 15, lkh = lane >> 4;

    const f32x4 fz = {0.f, 0.f, 0.f, 0.f};
    f32x4 acc[4][4];
    #pragma unroll
    for (int i = 0; i < 4; ++i)
        #pragma unroll
        for (int j = 0; j < 4; ++j) acc[i][j] = fz;

    int nk = K >> 5;
    for (int kc = 0; kc < nk; ++kc) {
        uint4 va0 = *(const uint4*)(A + a0 + kc * 32);
        uint4 va1 = *(const uint4*)(A + a1 + kc * 32);
        uint4 vb0 = *(const uint4*)(b0p + kc * 32);
        uint4 vb1 = *(const uint4*)(b1p + kc * 32);
        *(uint4*)&Al[rA * LDT + qA * 8]        = va0;
        *(uint4*)&Al[(rA + 64) * LDT + qA * 8] = va1;
        *(uint4*)&Bl[rA * LDT + qA * 8]        = vb0;
        *(uint4*)&Bl[(rA + 64) * LDT + qA * 8] = vb1;
        __syncthreads();
        short8 af[4], bfr[4];
        #pragma unroll
        for (int mi = 0; mi < 4; ++mi)
            af[mi] = *(const short8*)&Al[(wr * 64 + mi * 16 + lrow) * LDT + lkh * 8];
        #pragma unroll
        for (int ni = 0; ni < 4; ++ni)
            bfr[ni] = *(const short8*)&Bl[(wc * 64 + ni * 16 + lrow) * LDT + lkh * 8];
        #pragma unroll
        for (int mi = 0; mi < 4; ++mi)
            #pragma unroll
            for (int ni = 0; ni < 4; ++ni)
                acc[mi][ni] = __builtin_amdgcn_mfma_f32_16x16x32_bf16(
                    af[mi], bfr[ni], acc[mi][ni], 0, 0, 0);
        __syncthreads();
    }
    #pragma unroll
    for (int mi = 0; mi < 4; ++mi) {
        #pragma unroll
        for (int r = 0; r < 4; ++r) {
            int m = m0 + wr * 64 + mi * 16 + lkh * 4 + r;
            long rowoff = rowAdd ? (long)(m / rowAddDiv) * N : 0;
            #pragma unroll
            for (int ni = 0; ni < 4; ++ni) {
                int n = n0 + wc * 64 + ni * 16 + lrow;
                float v = acc[mi][ni][r];
                if (bias)   v += bias[n];
                if (rowAdd) v += rowAdd[rowoff + n];
                if (ACT)    v = fmaxf(v, 0.f);
                if (OUTM == 1)      ((ushort*)Cout)[(long)m * N + n] = f2bf(v);
                else if (OUTM == 2) ((ushort*)Cout)[(long)m * N + n] = f2h(v);
                else                ((float*)Cout)[(long)m * N + n] = v;
            }
        }
    }
}

// ---------------- fused Gdec GEMM + decode cell ----------------
__global__ __launch_bounds__(256) void k_gdec_fused(
    const ushort* __restrict__ A, int rowDiv, long sOuter, long sInner,
    const ushort* __restrict__ Bm,
    const float* __restrict__ hhdec,
    const float* __restrict__ cNb,
    ushort* __restrict__ hdec)
{
    constexpr int LDT = 40;
    __shared__ ushort Al[128 * LDT];
    __shared__ ushort Bl[128 * LDT];
    __shared__ ushort Zl[128 * 132];
    int tid = threadIdx.x;
    int j0 = blockIdx.x * 32;
    int m0 = blockIdx.y * 128;
    const int K = E_;

    int rA = tid >> 2, qA = tid & 3;
    int m_lo = m0 + rA, m_hi = m_lo + 64;
    long a0 = (long)(m_lo / rowDiv) * sOuter + (long)(m_lo % rowDiv) * sInner + qA * 8;
    long a1 = (long)(m_hi / rowDiv) * sOuter + (long)(m_hi % rowDiv) * sInner + qA * 8;
    int nr0 = rA, nr1 = rA + 64;
    const ushort* b0p = Bm + (long)((nr0 >> 5) * 256 + j0 + (nr0 & 31)) * K + qA * 8;
    const ushort* b1p = Bm + (long)((nr1 >> 5) * 256 + j0 + (nr1 & 31)) * K + qA * 8;

    int lane = tid & 63, wave = tid >> 6;
    int wr = wave >> 1, wc = wave & 1;
    int lrow = lane & 15, lkh = lane >> 4;

    const f32x4 fz = {0.f, 0.f, 0.f, 0.f};
    f32x4 acc[4][4];
    #pragma unroll
    for (int i = 0; i < 4; ++i)
        #pragma unroll
        for (int j = 0; j < 4; ++j) acc[i][j] = fz;

    for (int kc = 0; kc < K / 32; ++kc) {
        uint4 va0 = *(const uint4*)(A + a0 + kc * 32);
        uint4 va1 = *(const uint4*)(A + a1 + kc * 32);
        uint4 vb0 = *(const uint4*)(b0p + kc * 32);
        uint4 vb1 = *(const uint4*)(b1p + kc * 32);
        *(uint4*)&Al[rA * LDT + qA * 8]        = va0;
        *(uint4*)&Al[(rA + 64) * LDT + qA * 8] = va1;
        *(uint4*)&Bl[rA * LDT + qA * 8]        = vb0;
        *(uint4*)&Bl[(rA + 64) * LDT + qA * 8] = vb1;
        __syncthreads();
        short8 af[4], bfr[4];
        #pragma unroll
        for (int mi = 0; mi < 4; ++mi)
            af[mi] = *(const short8*)&Al[(wr * 64 + mi * 16 + lrow) * LDT + lkh * 8];
        #pragma unroll
        for (int ni = 0; ni < 4; ++ni)
            bfr[ni] = *(const short8*)&Bl[(wc * 64 + ni * 16 + lrow) * LDT + lkh * 8];
        #pragma unroll
        for (int mi = 0; mi < 4; ++mi)
            #pragma unroll
            for (int ni = 0; ni < 4; ++ni)
                acc[mi][ni] = __builtin_amdgcn_mfma_f32_16x16x32_bf16(
                    af[mi], bfr[ni], acc[mi][ni], 0, 0, 0);
        __syncthreads();
    }
    #pragma unroll
    for (int mi = 0; mi < 4; ++mi) {
        #pragma unroll
        for (int r = 0; r < 4; ++r) {
            int row = wr * 64 + mi * 16 + lkh * 4 + r;
            int bidx = (m0 + row) / T_;
            #pragma unroll
            for (int ni = 0; ni < 4; ++ni) {
                int col = wc * 64 + ni * 16 + lrow;
                float v = acc[mi][ni][r]
                        + hhdec[(long)bidx * G4 + (col >> 5) * 256 + j0 + (col & 31)];
                Zl[row * 132 + col] = f2bf(v);
            }
        }
    }
    __syncthreads();
    int jl = tid & 31, mb = tid >> 5;
    #pragma unroll
    for (int q = 0; q < 16; ++q) {
        int row = mb * 16 + q;
        int m = m0 + row;
        int bidx = m / T_;
        float gi = bf2f(Zl[row * 132 +      jl]);
        float gf = bf2f(Zl[row * 132 + 32 + jl]);
        float gg = bf2f(Zl[row * 132 + 64 + jl]);
        float go = bf2f(Zl[row * 132 + 96 + jl]);
        float cv = fsig(gf) * cNb[(long)bidx * H_ + j0 + jl] + fsig(gi) * ftanh(gg);
        hdec[(long)m * H_ + j0 + jl] = f2bf(fsig(go) * ftanh(cv));
    }
}

// ---------------- z2 GEMM with fused mlp3 epilogue ----------------
__global__ __launch_bounds__(256) void k_z2_fused(
    const ushort* __restrict__ A, const ushort* __restrict__ Bm,
    const float* __restrict__ b2, const float* __restrict__ W3,
    const float* __restrict__ b3, float* __restrict__ out)
{
    constexpr int LDT = 40;
    __shared__ ushort Al[128 * LDT];
    __shared__ ushort Bl[128 * LDT];
    __shared__ float Zl[128 * 132];
    int tid = threadIdx.x;
    int m0 = blockIdx.x * 128;
    const int K = P1_;

    int rA = tid >> 2, qA = tid & 3;
    const ushort* a0p = A + (long)(m0 + rA) * K + qA * 8;
    const ushort* a1p = A + (long)(m0 + rA + 64) * K + qA * 8;
    const ushort* b0p = Bm + (long)rA * K + qA * 8;
    const ushort* b1p = Bm + (long)(rA + 64) * K + qA * 8;

    int lane = tid & 63, wave = tid >> 6;
    int wr = wave >> 1, wc = wave & 1;
    int lrow = lane & 15, lkh = lane >> 4;

    const f32x4 fz = {0.f, 0.f, 0.f, 0.f};
    f32x4 acc[4][4];
    #pragma unroll
    for (int i = 0; i < 4; ++i)
        #pragma unroll
        for (int j = 0; j < 4; ++j) acc[i][j] = fz;

    for (int kc = 0; kc < K / 32; ++kc) {
        uint4 va0 = *(const uint4*)(a0p + kc * 32);
        uint4 va1 = *(const uint4*)(a1p + kc * 32);
        uint4 vb0 = *(const uint4*)(b0p + kc * 32);
        uint4 vb1 = *(const uint4*)(b1p + kc * 32);
        *(uint4*)&Al[rA * LDT + qA * 8]        = va0;
        *(uint4*)&Al[(rA + 64) * LDT + qA * 8] = va1;
        *(uint4*)&Bl[rA * LDT + qA * 8]        = vb0;
        *(uint4*)&Bl[(rA + 64) * LDT + qA * 8] = vb1;
        __syncthreads();
        short8 af[4], bfr[4];
        #pragma unroll
        for (int mi = 0; mi < 4; ++mi)
            af[mi] = *(const short8*)&Al[(wr * 64 + mi * 16 + lrow) * LDT + lkh * 8];
        #pragma unroll
        for (int ni = 0; ni < 4; ++ni)
            bfr[ni] = *(const short8*)&Bl[(wc * 64 + ni * 16 + lrow) * LDT + lkh * 8];
        #pragma unroll
        for (int mi = 0; mi < 4; ++mi)
            #pragma unroll
            for (int ni = 0; ni < 4; ++ni)
                acc[mi][ni] = __builtin_amdgcn_mfma_f32_16x16x32_bf16(
                    af[mi], bfr[ni], acc[mi][ni], 0, 0, 0);
        __syncthreads();
    }
    #pragma unroll
    for (int mi = 0; mi < 4; ++mi) {
        #pragma unroll
        for (int r = 0; r < 4; ++r) {
            int row = wr * 64 + mi * 16 + lkh * 4 + r;
            #pragma unroll
            for (int ni = 0; ni < 4; ++ni) {
                int col = wc * 64 + ni * 16 + lrow;
                Zl[row * 132 + col] = fmaxf(acc[mi][ni][r] + b2[col], 0.f);
            }
        }
    }
    __syncthreads();
    float w3a = W3[lane], w3b = W3[64 + lane], b3v = b3[0];
    for (int r = 0; r < 32; ++r) {
        int row = wave * 32 + r;
        float s = Zl[row * 132 + lane] * w3a + Zl[row * 132 + 64 + lane] * w3b;
        #pragma unroll
        for (int off = 32; off > 0; off >>= 1) s += __shfl_down(s, off);
        if (lane == 0) out[m0 + row] = fsig(s + b3v);
    }
}

// Persistent LSTM scan, W fully CU-resident (r13/r15-verified structure).
// 512 threads/block, 2 waves/SIMD; thread owns cols (tid, tid+512).
// W rows 0..NL2_-1 in LDS transposed [col][row]; rows NL2_..127 in VGPRs.
// Only change vs r15: __expf-based activations (fsig/ftanh).
__global__ __launch_bounds__(512, 2) void k_lstm_scan(
    const ushort* __restrict__ Xgh, const uint* __restrict__ WPu,
    float* __restrict__ hN, float* __restrict__ cN, ushort* __restrict__ hNb)
{
    extern __shared__ __align__(16) char smem[];
    uint*   Wl    = (uint*)smem;                    // [1024 cols][NL2_ rows]
    float*  act_s = (float*)(smem + NL2_ * 4096);   // 1024 f32
    uint*   h16u  = (uint*)(act_s + G4);            // 128 uints (packed f16 h)
    ushort* h16   = (ushort*)h16u;
    int tid = threadIdx.x;
    int b   = blockIdx.x;
    int cB  = tid + 512;

    for (int i = tid; i < NL2_ * 1024; i += 512) {
        int row = i >> 10, col = i & 1023;
        Wl[col * NL2_ + row] = WPu[(long)row * G4 + col];
    }
    uint wrA[NV2_], wrB[NV2_];
    #pragma unroll
    for (int i = 0; i < NV2_; ++i) {
        wrA[i] = WPu[(long)(NL2_ + i) * G4 + tid];
        wrB[i] = WPu[(long)(NL2_ + i) * G4 + cB];
    }
    if (tid < 128) h16u[tid] = 0;
    float c_r = 0.f;
    __syncthreads();

    int isTanhB = (tid >> 8) == 0;
    const ushort* xgp = Xgh + (long)b * T_ * G4;
    const uint* wcA = Wl + tid * NL2_;
    const uint* wcB = Wl + (tid + 512) * NL2_;

    for (int t = 0; t < T_; ++t) {
        float xvA = h2f(xgp[(long)t * G4 + tid]);
        float xvB = h2f(xgp[(long)t * G4 + cB]);
        float aA0 = 0.f, aA1 = 0.f, aB0 = 0.f, aB1 = 0.f;
        #pragma unroll
        for (int r4 = 0; r4 < NL2_ / 4; ++r4) {
            uint4 hh = *(const uint4*)(h16u + 4 * r4);
            uint4 wa = *(const uint4*)(wcA + 4 * r4);
            uint4 wb = *(const uint4*)(wcB + 4 * r4);
            aA0 = FDOT2(BCH2(wa.x), BCH2(hh.x), aA0); aB0 = FDOT2(BCH2(wb.x), BCH2(hh.x), aB0);
            aA1 = FDOT2(BCH2(wa.y), BCH2(hh.y), aA1); aB1 = FDOT2(BCH2(wb.y), BCH2(hh.y), aB1);
            aA0 = FDOT2(BCH2(wa.z), BCH2(hh.z), aA0); aB0 = FDOT2(BCH2(wb.z), BCH2(hh.z), aB0);
            aA1 = FDOT2(BCH2(wa.w), BCH2(hh.w), aA1); aB1 = FDOT2(BCH2(wb.w), BCH2(hh.w), aB1);
        }
        #pragma unroll
        for (int r4 = 0; r4 < NV2_ / 4; ++r4) {
            uint4 hh = *(const uint4*)(h16u + NL2_ + 4 * r4);
            aA0 = FDOT2(BCH2(wrA[4 * r4 + 0]), BCH2(hh.x), aA0);
            aB0 = FDOT2(BCH2(wrB[4 * r4 + 0]), BCH2(hh.x), aB0);
            aA1 = FDOT2(BCH2(wrA[4 * r4 + 1]), BCH2(hh.y), aA1);
            aB1 = FDOT2(BCH2(wrB[4 * r4 + 1]), BCH2(hh.y), aB1);
            aA0 = FDOT2(BCH2(wrA[4 * r4 + 2]), BCH2(hh.z), aA0);
            aB0 = FDOT2(BCH2(wrB[4 * r4 + 2]), BCH2(hh.z), aB0);
            aA1 = FDOT2(BCH2(wrA[4 * r4 + 3]), BCH2(hh.w), aA1);
            aB1 = FDOT2(BCH2(wrB[4 * r4 + 3]), BCH2(hh.w), aB1);
        }
        float aA = aA0 + aA1, aB = aB0 + aB1;
        act_s[tid] = fsig(aA + xvA);
        float gB = aB + xvB;
        act_s[cB] = isTanhB ? ftanh(gB) : fsig(gB);
        __syncthreads();
        if (tid < H_) {
            float cn = act_s[H_ + tid] * c_r + act_s[tid] * act_s[2 * H_ + tid];
            c_r = cn;
            float h = act_s[3 * H_ + tid] * ftanh(cn);
            h16[tid] = f2h(h);
            if (t == T_ - 1) {
                hN[(long)b * H_ + tid] = h;
                cN[(long)b * H_ + tid] = c_r;
                hNb[(long)b * H_ + tid] = f2bf(h);
            }
        }
        __syncthreads();
    }
}

extern "C" void kernel_launch(void* const* d_in, const int* in_sizes, int n_in,
                              void* d_out, int out_size, void* d_ws, size_t ws_size,
                              hipStream_t stream)
{
    const int*   x    = (const int*)d_in[0];
    const float* emb  = (const float*)d_in[1];
    const float* W_ih = (const float*)d_in[2];
    const float* W_hh = (const float*)d_in[3];
    const float* b_ih = (const float*)d_in[4];
    const float* b_hh = (const float*)d_in[5];
    const float* W1   = (const float*)d_in[6];
    const float* b1   = (const float*)d_in[7];
    const float* W2   = (const float*)d_in[8];
    const float* b2   = (const float*)d_in[9];
    const float* W3   = (const float*)d_in[10];
    const float* b3   = (const float*)d_in[11];
    float* out = (float*)d_out;

    float* ws = (float*)d_ws;
    ushort* ebf   = (ushort*)ws;                    // 6,553,600 ush
    ushort* Xgh   = (ushort*)(ws + 3276800);        // 26,214,400 ush (fp16 Xg)
    ushort* hdecb = (ushort*)(ws + 16384000);       // 6,553,600 ush
    ushort* z1b   = (ushort*)(ws + 19660800);       // 13,107,200 ush
    float* bsum  = ws + 26214400;                   // 1024
    float* hN    = bsum + 1024;                     // 65,536
    float* cN    = hN + 65536;                      // 65,536
    ushort* hNb  = (ushort*)(cN + 65536);           // 65,536 ush
    float* hhdec = cN + 65536 + 32768;              // 262,144
    uint*  WPu   = (uint*)(hhdec + 262144);         // 131,072 uints
    ushort* Wihb = (ushort*)(WPu + 131072);         // 131,072 ush
    ushort* Whhb = Wihb + 131072;                   // 262,144 ush
    ushort* W1T  = Whhb + 262144;                   // 131,072 ush
    ushort* W2T  = W1T + 131072;                    // 65,536 ush

    // all independent prep + gather in ONE launch
    k_prep_all<<<1988 + B_ * S_ / 2, 256, 0, stream>>>(
        W_hh, WPu, W1, W1T, W2, W2T, W_ih, Wihb, Whhb,
        b_ih, b_hh, bsum, x, emb, ebf);

    // Xg = e_hist @ W_ih^T + bsum  -> fp16 (feeds the scan)
    k_gemm_mfma<0, 2><<<dim3(G4 / 128, (B_ * T_) / 128), 256, 0, stream>>>(
        ebf, T_, (long)S_ * E_, (long)E_, Wihb, bsum, nullptr, 1,
        Xgh, G4, E_);

    // persistent scan: W fully resident; writes hN (f32), cN, hNb (bf16)
    size_t scan_smem = (size_t)NL2_ * 4096 + G4 * sizeof(float) + 128 * sizeof(uint);
    k_lstm_scan<<<B_, 512, scan_smem, stream>>>(Xgh, WPu, hN, cN, hNb);

    // hhdec = hN @ W_hh^T + bsum  (MFMA, M=256)
    k_gemm_mfma<0, 0><<<dim3(G4 / 128, B_ / 128), 256, 0, stream>>>(
        hNb, B_, 0L, (long)H_, Whhb, bsum, nullptr, 1,
        hhdec, G4, H_);

    // fused Gdec GEMM + decode cell -> hdecb (Gdec gates never hit HBM)
    k_gdec_fused<<<dim3(H_ / 32, (B_ * T_) / 128), 256, 0, stream>>>(
        ebf + T_ * E_, T_, (long)S_ * E_, (long)E_, Wihb, hhdec, cN, hdecb);

    // z1 = relu(hdec @ W1 + b1) -> bf16
    k_gemm_mfma<1, 1><<<dim3(P1_ / 128, (B_ * T_) / 128), 256, 0, stream>>>(
        hdecb, B_ * T_, 0L, (long)H_, W1T, b1, nullptr, 1,
        z1b, P1_, H_);

    // z2 GEMM + mlp3 fused -> out
    k_z2_fused<<<(B_ * T_) / 128, 256, 0, stream>>>(z1b, W2T, b2, W3, b3, out);
}

// Round 17
// 357.383 us; speedup vs baseline: 7.6153x; 1.0590x over previous
//
#include <hip/hip_runtime.h>
#include <hip/hip_bf16.h>
#include <math.h>

#define B_  256
#define S_  200
#define F_  10
#define T_  100
#define E_  128
#define H_  256
#define G4  1024   // 4*H
#define P1_ 512
#define P2_ 128

typedef __attribute__((ext_vector_type(8))) short short8;
typedef __attribute__((ext_vector_type(4))) float f32x4;
typedef _Float16 half2f __attribute__((ext_vector_type(2)));

#if __has_builtin(__builtin_amdgcn_fdot2)
#define FDOT2(w2, h2, acc) __builtin_amdgcn_fdot2((w2), (h2), (acc), false)
#else
#define FDOT2(w2, h2, acc) ((acc) + (float)((w2)[0]) * (float)((h2)[0]) + (float)((w2)[1]) * (float)((h2)[1]))
#endif
#define BCH2(u) __builtin_bit_cast(half2f, (u))

// scan W placement (kpair rows of 1024 uints): 36 in LDS, 92 in VGPRs (x2 cols)
// HARD CONSTRAINT (r14 lesson): arch VGPR cap is 256/thread. 92*2=184 + ~40 fits.
#define NL2_ 36
#define NV2_ 92

__device__ __forceinline__ float fsig(float x) { return 1.0f / (1.0f + __expf(-x)); }
__device__ __forceinline__ float ftanh(float x) { return 1.0f - 2.0f / (__expf(2.0f * x) + 1.0f); }
__device__ __forceinline__ float bf2f(ushort u) { return __uint_as_float(((uint)u) << 16); }
__device__ __forceinline__ ushort f2bf(float f) {
    __hip_bfloat16 v = __float2bfloat16(f);
    return *(ushort*)&v;
}
__device__ __forceinline__ ushort f2h(float f) {
    _Float16 h = (_Float16)f;
    return __builtin_bit_cast(ushort, h);
}
__device__ __forceinline__ float h2f(ushort u) {
    return (float)__builtin_bit_cast(_Float16, u);
}

// ---------------- mega prep kernel (r16-verified) ----------------
__global__ __launch_bounds__(256) void k_prep_all(
    const float* __restrict__ W_hh, uint* __restrict__ WPu,
    const float* __restrict__ W1, ushort* __restrict__ W1T,
    const float* __restrict__ W2, ushort* __restrict__ W2T,
    const float* __restrict__ W_ih, ushort* __restrict__ Wihb,
    ushort* __restrict__ Whhb,
    const float* __restrict__ b_ih, const float* __restrict__ b_hh,
    float* __restrict__ bsum,
    const int* __restrict__ x, const float* __restrict__ emb,
    ushort* __restrict__ ebf)
{
    __shared__ float t[32][33];
    int blk = blockIdx.x;
    int tid = threadIdx.x;
    if (blk < 256) {
        int k0 = (blk & 7) * 32, c0 = (blk >> 3) * 32;
        int lk = tid & 31, lc8 = tid >> 5;
        #pragma unroll
        for (int i = 0; i < 4; ++i)
            t[lc8 + 8 * i][lk] = W_hh[(long)(c0 + lc8 + 8 * i) * 256 + k0 + lk];
        __syncthreads();
        int kpl = tid >> 4, ccl = tid & 15;
        #pragma unroll
        for (int hf = 0; hf < 2; ++hf) {
            int c = ccl + 16 * hf;
            uint lo = f2h(t[c][2 * kpl]);
            uint hi = f2h(t[c][2 * kpl + 1]);
            WPu[(long)(k0 / 2 + kpl) * G4 + c0 + c] = lo | (hi << 16);
        }
    } else if (blk < 448) {
        const float* W; ushort* WT; int R, C, idx;
        if (blk < 384) { W = W1; WT = W1T; R = H_;  C = P1_; idx = blk - 256;
                         idx = (idx & 15) | ((idx >> 4) << 8); }
        else           { W = W2; WT = W2T; R = P1_; C = P2_; idx = blk - 384;
                         idx = (idx & 3) | ((idx >> 2) << 8); }
        int c0 = (idx & 255) * 32, r0 = (idx >> 8) * 32;
        int lc = tid & 31, lr = tid >> 5;
        #pragma unroll
        for (int i = 0; i < 4; ++i)
            t[lr + 8 * i][lc] = W[(long)(r0 + lr + 8 * i) * C + c0 + lc];
        __syncthreads();
        #pragma unroll
        for (int i = 0; i < 4; ++i)
            WT[(long)(c0 + lr + 8 * i) * R + r0 + lc] = f2bf(t[lc][lr + 8 * i]);
    } else if (blk < 960) {
        int i = (blk - 448) * 256 + tid;
        Wihb[i] = f2bf(W_ih[i]);
    } else if (blk < 1984) {
        int i = (blk - 960) * 256 + tid;
        Whhb[i] = f2bf(W_hh[i]);
    } else if (blk < 1988) {
        int i = (blk - 1984) * 256 + tid;
        bsum[i] = b_ih[i] + b_hh[i];
    } else {
        int bs = (blk - 1988) * 2 + (tid >> 7);
        int e  = tid & 127;
        const int* xr = x + (long)bs * F_;
        float acc = 0.f;
        #pragma unroll
        for (int f = 0; f < F_; ++f) acc += emb[(long)xr[f] * E_ + e];
        ebf[(long)bs * E_ + e] = f2bf(acc * (1.0f / F_));
    }
}

// ---------------- bf16 MFMA GEMM. OUTM: 0=f32, 1=bf16, 2=f16 ----------------
template<int ACT, int OUTM>
__global__ __launch_bounds__(256) void k_gemm_mfma(
    const ushort* __restrict__ A, int rowDiv, long sOuter, long sInner,
    const ushort* __restrict__ Bm,
    const float* __restrict__ bias,
    const float* __restrict__ rowAdd, int rowAddDiv,
    void* __restrict__ Cout, int N, int K)
{
    constexpr int LDT = 40;
    __shared__ ushort Al[128 * LDT];
    __shared__ ushort Bl[128 * LDT];
    int tid = threadIdx.x;
    int n0 = blockIdx.x * 128;
    int m0 = blockIdx.y * 128;

    int rA = tid >> 2, qA = tid & 3;
    int m_lo = m0 + rA, m_hi = m_lo + 64;
    long a0 = (long)(m_lo / rowDiv) * sOuter + (long)(m_lo % rowDiv) * sInner + qA * 8;
    long a1 = (long)(m_hi / rowDiv) * sOuter + (long)(m_hi % rowDiv) * sInner + qA * 8;
    const ushort* b0p = Bm + (long)(n0 + rA) * K + qA * 8;
    const ushort* b1p = Bm + (long)(n0 + rA + 64) * K + qA * 8;

    int lane = tid & 63, wave = tid >> 6;
    int wr = wave >> 1, wc = wave & 1;
    int lrow = lane & 15, lkh = lane >> 4;

    const f32x4 fz = {0.f, 0.f, 0.f, 0.f};
    f32x4 acc[4][4];
    #pragma unroll
    for (int i = 0; i < 4; ++i)
        #pragma unroll
        for (int j = 0; j < 4; ++j) acc[i][j] = fz;

    int nk = K >> 5;
    for (int kc = 0; kc < nk; ++kc) {
        uint4 va0 = *(const uint4*)(A + a0 + kc * 32);
        uint4 va1 = *(const uint4*)(A + a1 + kc * 32);
        uint4 vb0 = *(const uint4*)(b0p + kc * 32);
        uint4 vb1 = *(const uint4*)(b1p + kc * 32);
        *(uint4*)&Al[rA * LDT + qA * 8]        = va0;
        *(uint4*)&Al[(rA + 64) * LDT + qA * 8] = va1;
        *(uint4*)&Bl[rA * LDT + qA * 8]        = vb0;
        *(uint4*)&Bl[(rA + 64) * LDT + qA * 8] = vb1;
        __syncthreads();
        short8 af[4], bfr[4];
        #pragma unroll
        for (int mi = 0; mi < 4; ++mi)
            af[mi] = *(const short8*)&Al[(wr * 64 + mi * 16 + lrow) * LDT + lkh * 8];
        #pragma unroll
        for (int ni = 0; ni < 4; ++ni)
            bfr[ni] = *(const short8*)&Bl[(wc * 64 + ni * 16 + lrow) * LDT + lkh * 8];
        #pragma unroll
        for (int mi = 0; mi < 4; ++mi)
            #pragma unroll
            for (int ni = 0; ni < 4; ++ni)
                acc[mi][ni] = __builtin_amdgcn_mfma_f32_16x16x32_bf16(
                    af[mi], bfr[ni], acc[mi][ni], 0, 0, 0);
        __syncthreads();
    }
    #pragma unroll
    for (int mi = 0; mi < 4; ++mi) {
        #pragma unroll
        for (int r = 0; r < 4; ++r) {
            int m = m0 + wr * 64 + mi * 16 + lkh * 4 + r;
            long rowoff = rowAdd ? (long)(m / rowAddDiv) * N : 0;
            #pragma unroll
            for (int ni = 0; ni < 4; ++ni) {
                int n = n0 + wc * 64 + ni * 16 + lrow;
                float v = acc[mi][ni][r];
                if (bias)   v += bias[n];
                if (rowAdd) v += rowAdd[rowoff + n];
                if (ACT)    v = fmaxf(v, 0.f);
                if (OUTM == 1)      ((ushort*)Cout)[(long)m * N + n] = f2bf(v);
                else if (OUTM == 2) ((ushort*)Cout)[(long)m * N + n] = f2h(v);
                else                ((float*)Cout)[(long)m * N + n] = v;
            }
        }
    }
}

// ---------------- fused Gdec GEMM + decode cell (r15-verified) ----------------
__global__ __launch_bounds__(256) void k_gdec_fused(
    const ushort* __restrict__ A, int rowDiv, long sOuter, long sInner,
    const ushort* __restrict__ Bm,
    const float* __restrict__ hhdec,
    const float* __restrict__ cNb,
    ushort* __restrict__ hdec)
{
    constexpr int LDT = 40;
    __shared__ ushort Al[128 * LDT];
    __shared__ ushort Bl[128 * LDT];
    __shared__ ushort Zl[128 * 132];
    int tid = threadIdx.x;
    int j0 = blockIdx.x * 32;
    int m0 = blockIdx.y * 128;
    const int K = E_;

    int rA = tid >> 2, qA = tid & 3;
    int m_lo = m0 + rA, m_hi = m_lo + 64;
    long a0 = (long)(m_lo / rowDiv) * sOuter + (long)(m_lo % rowDiv) * sInner + qA * 8;
    long a1 = (long)(m_hi / rowDiv) * sOuter + (long)(m_hi % rowDiv) * sInner + qA * 8;
    int nr0 = rA, nr1 = rA + 64;
    const ushort* b0p = Bm + (long)((nr0 >> 5) * 256 + j0 + (nr0 & 31)) * K + qA * 8;
    const ushort* b1p = Bm + (long)((nr1 >> 5) * 256 + j0 + (nr1 & 31)) * K + qA * 8;

    int lane = tid & 63, wave = tid >> 6;
    int wr = wave >> 1, wc = wave & 1;
    int lrow = lane & 15, lkh = lane >> 4;

    const f32x4 fz = {0.f, 0.f, 0.f, 0.f};
    f32x4 acc[4][4];
    #pragma unroll
    for (int i = 0; i < 4; ++i)
        #pragma unroll
        for (int j = 0; j < 4; ++j) acc[i][j] = fz;

    for (int kc = 0; kc < K / 32; ++kc) {
        uint4 va0 = *(const uint4*)(A + a0 + kc * 32);
        uint4 va1 = *(const uint4*)(A + a1 + kc * 32);
        uint4 vb0 = *(const uint4*)(b0p + kc * 32);
        uint4 vb1 = *(const uint4*)(b1p + kc * 32);
        *(uint4*)&Al[rA * LDT + qA * 8]        = va0;
        *(uint4*)&Al[(rA + 64) * LDT + qA * 8] = va1;
        *(uint4*)&Bl[rA * LDT + qA * 8]        = vb0;
        *(uint4*)&Bl[(rA + 64) * LDT + qA * 8] = vb1;
        __syncthreads();
        short8 af[4], bfr[4];
        #pragma unroll
        for (int mi = 0; mi < 4; ++mi)
            af[mi] = *(const short8*)&Al[(wr * 64 + mi * 16 + lrow) * LDT + lkh * 8];
        #pragma unroll
        for (int ni = 0; ni < 4; ++ni)
            bfr[ni] = *(const short8*)&Bl[(wc * 64 + ni * 16 + lrow) * LDT + lkh * 8];
        #pragma unroll
        for (int mi = 0; mi < 4; ++mi)
            #pragma unroll
            for (int ni = 0; ni < 4; ++ni)
                acc[mi][ni] = __builtin_amdgcn_mfma_f32_16x16x32_bf16(
                    af[mi], bfr[ni], acc[mi][ni], 0, 0, 0);
        __syncthreads();
    }
    #pragma unroll
    for (int mi = 0; mi < 4; ++mi) {
        #pragma unroll
        for (int r = 0; r < 4; ++r) {
            int row = wr * 64 + mi * 16 + lkh * 4 + r;
            int bidx = (m0 + row) / T_;
            #pragma unroll
            for (int ni = 0; ni < 4; ++ni) {
                int col = wc * 64 + ni * 16 + lrow;
                float v = acc[mi][ni][r]
                        + hhdec[(long)bidx * G4 + (col >> 5) * 256 + j0 + (col & 31)];
                Zl[row * 132 + col] = f2bf(v);
            }
        }
    }
    __syncthreads();
    int jl = tid & 31, mb = tid >> 5;
    #pragma unroll
    for (int q = 0; q < 16; ++q) {
        int row = mb * 16 + q;
        int m = m0 + row;
        int bidx = m / T_;
        float gi = bf2f(Zl[row * 132 +      jl]);
        float gf = bf2f(Zl[row * 132 + 32 + jl]);
        float gg = bf2f(Zl[row * 132 + 64 + jl]);
        float go = bf2f(Zl[row * 132 + 96 + jl]);
        float cv = fsig(gf) * cNb[(long)bidx * H_ + j0 + jl] + fsig(gi) * ftanh(gg);
        hdec[(long)m * H_ + j0 + jl] = f2bf(fsig(go) * ftanh(cv));
    }
}

// ---------------- fused MLP: z1 -> z2 -> out, one kernel ----------------
// Per block: 128 m-rows. Phase 1: z1 tile (128x512) in 4 n-passes -> LDS bf16
// [row][520]. Phase 2: z2 = relu(z1@W2T+b2) with A-frags straight from LDS;
// z2 f32 tile overwrites dead z1 LDS; wave-per-row W3 reduction -> out.
#define Z1S 520
__global__ __launch_bounds__(256) void k_mlp_fused(
    const ushort* __restrict__ A,       // hdecb [M][256]
    const ushort* __restrict__ W1T,     // [512][256] bf16
    const float* __restrict__ b1,
    const ushort* __restrict__ W2T,     // [128][512] bf16
    const float* __restrict__ b2,
    const float* __restrict__ W3, const float* __restrict__ b3,
    float* __restrict__ out)
{
    extern __shared__ __align__(16) char smem[];
    ushort* z1l = (ushort*)smem;              // 128*520 ush = 133,120 B
    ushort* Al  = z1l + 128 * Z1S;            // 128*40 ush = 10,240 B
    ushort* Bl  = Al + 128 * 40;              // 10,240 B  (total 153,600)
    int tid = threadIdx.x;
    int m0 = blockIdx.x * 128;

    int rA = tid >> 2, qA = tid & 3;
    int lane = tid & 63, wave = tid >> 6;
    int wr = wave >> 1, wc = wave & 1;
    int lrow = lane & 15, lkh = lane >> 4;
    const f32x4 fz = {0.f, 0.f, 0.f, 0.f};

    // ---- phase 1: z1 = relu(hdec @ W1 + b1), 4 n-passes of 128 ----
    for (int nt = 0; nt < 4; ++nt) {
        f32x4 acc[4][4];
        #pragma unroll
        for (int i = 0; i < 4; ++i)
            #pragma unroll
            for (int j = 0; j < 4; ++j) acc[i][j] = fz;
        for (int kc = 0; kc < H_ / 32; ++kc) {
            uint4 va0 = *(const uint4*)(A + (long)(m0 + rA) * H_ + kc * 32 + qA * 8);
            uint4 va1 = *(const uint4*)(A + (long)(m0 + rA + 64) * H_ + kc * 32 + qA * 8);
            uint4 vb0 = *(const uint4*)(W1T + (long)(nt * 128 + rA) * H_ + kc * 32 + qA * 8);
            uint4 vb1 = *(const uint4*)(W1T + (long)(nt * 128 + rA + 64) * H_ + kc * 32 + qA * 8);
            *(uint4*)&Al[rA * 40 + qA * 8]        = va0;
            *(uint4*)&Al[(rA + 64) * 40 + qA * 8] = va1;
            *(uint4*)&Bl[rA * 40 + qA * 8]        = vb0;
            *(uint4*)&Bl[(rA + 64) * 40 + qA * 8] = vb1;
            __syncthreads();
            short8 af[4], bfr[4];
            #pragma unroll
            for (int mi = 0; mi < 4; ++mi)
                af[mi] = *(const short8*)&Al[(wr * 64 + mi * 16 + lrow) * 40 + lkh * 8];
            #pragma unroll
            for (int ni = 0; ni < 4; ++ni)
                bfr[ni] = *(const short8*)&Bl[(wc * 64 + ni * 16 + lrow) * 40 + lkh * 8];
            #pragma unroll
            for (int mi = 0; mi < 4; ++mi)
                #pragma unroll
                for (int ni = 0; ni < 4; ++ni)
                    acc[mi][ni] = __builtin_amdgcn_mfma_f32_16x16x32_bf16(
                        af[mi], bfr[ni], acc[mi][ni], 0, 0, 0);
            __syncthreads();
        }
        #pragma unroll
        for (int mi = 0; mi < 4; ++mi) {
            #pragma unroll
            for (int r = 0; r < 4; ++r) {
                int row = wr * 64 + mi * 16 + lkh * 4 + r;
                #pragma unroll
                for (int ni = 0; ni < 4; ++ni) {
                    int col = nt * 128 + wc * 64 + ni * 16 + lrow;
                    z1l[row * Z1S + col] = f2bf(fmaxf(acc[mi][ni][r] + b1[col], 0.f));
                }
            }
        }
    }
    __syncthreads();

    // ---- phase 2: z2 = relu(z1l @ W2T + b2), K=512 ----
    f32x4 acc[4][4];
    #pragma unroll
    for (int i = 0; i < 4; ++i)
        #pragma unroll
        for (int j = 0; j < 4; ++j) acc[i][j] = fz;
    for (int kc = 0; kc < P1_ / 32; ++kc) {
        uint4 vb0 = *(const uint4*)(W2T + (long)rA * P1_ + kc * 32 + qA * 8);
        uint4 vb1 = *(const uint4*)(W2T + (long)(rA + 64) * P1_ + kc * 32 + qA * 8);
        *(uint4*)&Bl[rA * 40 + qA * 8]        = vb0;
        *(uint4*)&Bl[(rA + 64) * 40 + qA * 8] = vb1;
        __syncthreads();
        short8 af[4], bfr[4];
        #pragma unroll
        for (int mi = 0; mi < 4; ++mi)
            af[mi] = *(const short8*)&z1l[(wr * 64 + mi * 16 + lrow) * Z1S + kc * 32 + lkh * 8];
        #pragma unroll
        for (int ni = 0; ni < 4; ++ni)
            bfr[ni] = *(const short8*)&Bl[(wc * 64 + ni * 16 + lrow) * 40 + lkh * 8];
        #pragma unroll
        for (int mi = 0; mi < 4; ++mi)
            #pragma unroll
            for (int ni = 0; ni < 4; ++ni)
                acc[mi][ni] = __builtin_amdgcn_mfma_f32_16x16x32_bf16(
                    af[mi], bfr[ni], acc[mi][ni], 0, 0, 0);
        __syncthreads();
    }
    // z2 f32 tile into the (now dead) z1l region
    float* Zf = (float*)z1l;   // 128*132 f32 = 67.6 KB < 133 KB
    #pragma unroll
    for (int mi = 0; mi < 4; ++mi) {
        #pragma unroll
        for (int r = 0; r < 4; ++r) {
            int row = wr * 64 + mi * 16 + lkh * 4 + r;
            #pragma unroll
            for (int ni = 0; ni < 4; ++ni) {
                int col = wc * 64 + ni * 16 + lrow;
                Zf[row * 132 + col] = fmaxf(acc[mi][ni][r] + b2[col], 0.f);
            }
        }
    }
    __syncthreads();
    float w3a = W3[lane], w3b = W3[64 + lane], b3v = b3[0];
    for (int r = 0; r < 32; ++r) {
        int row = wave * 32 + r;
        float s = Zf[row * 132 + lane] * w3a + Zf[row * 132 + 64 + lane] * w3b;
        #pragma unroll
        for (int off = 32; off > 0; off >>= 1) s += __shfl_down(s, off);
        if (lane == 0) out[m0 + row] = fsig(s + b3v);
    }
}

// Persistent LSTM scan, W fully CU-resident (r13/r16-verified structure).
__global__ __launch_bounds__(512, 2) void k_lstm_scan(
    const ushort* __restrict__ Xgh, const uint* __restrict__ WPu,
    float* __restrict__ cN, ushort* __restrict__ hNb)
{
    extern __shared__ __align__(16) char smem[];
    uint*   Wl    = (uint*)smem;
    float*  act_s = (float*)(smem + NL2_ * 4096);
    uint*   h16u  = (uint*)(act_s + G4);
    ushort* h16   = (ushort*)h16u;
    int tid = threadIdx.x;
    int b   = blockIdx.x;
    int cB  = tid + 512;

    for (int i = tid; i < NL2_ * 1024; i += 512) {
        int row = i >> 10, col = i & 1023;
        Wl[col * NL2_ + row] = WPu[(long)row * G4 + col];
    }
    uint wrA[NV2_], wrB[NV2_];
    #pragma unroll
    for (int i = 0; i < NV2_; ++i) {
        wrA[i] = WPu[(long)(NL2_ + i) * G4 + tid];
        wrB[i] = WPu[(long)(NL2_ + i) * G4 + cB];
    }
    if (tid < 128) h16u[tid] = 0;
    float c_r = 0.f;
    __syncthreads();

    int isTanhB = (tid >> 8) == 0;
    const ushort* xgp = Xgh + (long)b * T_ * G4;
    const uint* wcA = Wl + tid * NL2_;
    const uint* wcB = Wl + (tid + 512) * NL2_;

    for (int t = 0; t < T_; ++t) {
        float xvA = h2f(xgp[(long)t * G4 + tid]);
        float xvB = h2f(xgp[(long)t * G4 + cB]);
        float aA0 = 0.f, aA1 = 0.f, aB0 = 0.f, aB1 = 0.f;
        #pragma unroll
        for (int r4 = 0; r4 < NL2_ / 4; ++r4) {
            uint4 hh = *(const uint4*)(h16u + 4 * r4);
            uint4 wa = *(const uint4*)(wcA + 4 * r4);
            uint4 wb = *(const uint4*)(wcB + 4 * r4);
            aA0 = FDOT2(BCH2(wa.x), BCH2(hh.x), aA0); aB0 = FDOT2(BCH2(wb.x), BCH2(hh.x), aB0);
            aA1 = FDOT2(BCH2(wa.y), BCH2(hh.y), aA1); aB1 = FDOT2(BCH2(wb.y), BCH2(hh.y), aB1);
            aA0 = FDOT2(BCH2(wa.z), BCH2(hh.z), aA0); aB0 = FDOT2(BCH2(wb.z), BCH2(hh.z), aB0);
            aA1 = FDOT2(BCH2(wa.w), BCH2(hh.w), aA1); aB1 = FDOT2(BCH2(wb.w), BCH2(hh.w), aB1);
        }
        #pragma unroll
        for (int r4 = 0; r4 < NV2_ / 4; ++r4) {
            uint4 hh = *(const uint4*)(h16u + NL2_ + 4 * r4);
            aA0 = FDOT2(BCH2(wrA[4 * r4 + 0]), BCH2(hh.x), aA0);
            aB0 = FDOT2(BCH2(wrB[4 * r4 + 0]), BCH2(hh.x), aB0);
            aA1 = FDOT2(BCH2(wrA[4 * r4 + 1]), BCH2(hh.y), aA1);
            aB1 = FDOT2(BCH2(wrB[4 * r4 + 1]), BCH2(hh.y), aB1);
            aA0 = FDOT2(BCH2(wrA[4 * r4 + 2]), BCH2(hh.z), aA0);
            aB0 = FDOT2(BCH2(wrB[4 * r4 + 2]), BCH2(hh.z), aB0);
            aA1 = FDOT2(BCH2(wrA[4 * r4 + 3]), BCH2(hh.w), aA1);
            aB1 = FDOT2(BCH2(wrB[4 * r4 + 3]), BCH2(hh.w), aB1);
        }
        float aA = aA0 + aA1, aB = aB0 + aB1;
        act_s[tid] = fsig(aA + xvA);
        float gB = aB + xvB;
        act_s[cB] = isTanhB ? ftanh(gB) : fsig(gB);
        __syncthreads();
        if (tid < H_) {
            float cn = act_s[H_ + tid] * c_r + act_s[tid] * act_s[2 * H_ + tid];
            c_r = cn;
            float h = act_s[3 * H_ + tid] * ftanh(cn);
            h16[tid] = f2h(h);
            if (t == T_ - 1) {
                cN[(long)b * H_ + tid] = c_r;
                hNb[(long)b * H_ + tid] = f2bf(h);
            }
        }
        __syncthreads();
    }
}

extern "C" void kernel_launch(void* const* d_in, const int* in_sizes, int n_in,
                              void* d_out, int out_size, void* d_ws, size_t ws_size,
                              hipStream_t stream)
{
    const int*   x    = (const int*)d_in[0];
    const float* emb  = (const float*)d_in[1];
    const float* W_ih = (const float*)d_in[2];
    const float* W_hh = (const float*)d_in[3];
    const float* b_ih = (const float*)d_in[4];
    const float* b_hh = (const float*)d_in[5];
    const float* W1   = (const float*)d_in[6];
    const float* b1   = (const float*)d_in[7];
    const float* W2   = (const float*)d_in[8];
    const float* b2   = (const float*)d_in[9];
    const float* W3   = (const float*)d_in[10];
    const float* b3   = (const float*)d_in[11];
    float* out = (float*)d_out;

    float* ws = (float*)d_ws;
    ushort* ebf   = (ushort*)ws;                    // 6,553,600 ush
    ushort* Xgh   = (ushort*)(ws + 3276800);        // 26,214,400 ush (fp16 Xg)
    ushort* hdecb = (ushort*)(ws + 16384000);       // 6,553,600 ush
    float* bsum  = ws + 26214400;                   // 1024
    float* cN    = bsum + 1024;                     // 65,536
    ushort* hNb  = (ushort*)(cN + 65536);           // 65,536 ush
    float* hhdec = cN + 65536 + 32768;              // 262,144
    uint*  WPu   = (uint*)(hhdec + 262144);         // 131,072 uints
    ushort* Wihb = (ushort*)(WPu + 131072);         // 131,072 ush
    ushort* Whhb = Wihb + 131072;                   // 262,144 ush
    ushort* W1T  = Whhb + 262144;                   // 131,072 ush
    ushort* W2T  = W1T + 131072;                    // 65,536 ush

    // all independent prep + gather in ONE launch
    k_prep_all<<<1988 + B_ * S_ / 2, 256, 0, stream>>>(
        W_hh, WPu, W1, W1T, W2, W2T, W_ih, Wihb, Whhb,
        b_ih, b_hh, bsum, x, emb, ebf);

    // Xg = e_hist @ W_ih^T + bsum  -> fp16 (feeds the scan)
    k_gemm_mfma<0, 2><<<dim3(G4 / 128, (B_ * T_) / 128), 256, 0, stream>>>(
        ebf, T_, (long)S_ * E_, (long)E_, Wihb, bsum, nullptr, 1,
        Xgh, G4, E_);

    // persistent scan: W fully resident; writes cN (f32), hNb (bf16)
    size_t scan_smem = (size_t)NL2_ * 4096 + G4 * sizeof(float) + 128 * sizeof(uint);
    k_lstm_scan<<<B_, 512, scan_smem, stream>>>(Xgh, WPu, cN, hNb);

    // hhdec = hN @ W_hh^T + bsum  (MFMA, M=256)
    k_gemm_mfma<0, 0><<<dim3(G4 / 128, B_ / 128), 256, 0, stream>>>(
        hNb, B_, 0L, (long)H_, Whhb, bsum, nullptr, 1,
        hhdec, G4, H_);

    // fused Gdec GEMM + decode cell -> hdecb
    k_gdec_fused<<<dim3(H_ / 32, (B_ * T_) / 128), 256, 0, stream>>>(
        ebf + T_ * E_, T_, (long)S_ * E_, (long)E_, Wihb, hhdec, cN, hdecb);

    // fused MLP: z1 -> z2 -> out, one kernel (z1 never hits HBM)
    size_t mlp_smem = (size_t)128 * Z1S * 2 + 2 * 128 * 40 * 2;
    k_mlp_fused<<<(B_ * T_) / 128, 256, mlp_smem, stream>>>(
        hdecb, W1T, b1, W2T, b2, W3, b3, out);
}